// Round 5
// baseline (277.847 us; speedup 1.0000x reference)
//
#include <hip/hip_runtime.h>

typedef __attribute__((ext_vector_type(8))) short bf16x8;
typedef __attribute__((ext_vector_type(4))) float f32x4;
typedef unsigned short u16;

#define MFMA16(a, b, c) __builtin_amdgcn_mfma_f32_16x16x32_bf16(a, b, c, 0, 0, 0)

__device__ __forceinline__ u16 f2b(float f) {
  union { float f; unsigned u; } a; a.f = f;
  return (u16)((a.u + 0x7FFFu + ((a.u >> 16) & 1u)) >> 16);
}
__device__ __forceinline__ float b2f(u16 u) {
  union { unsigned u; float f; } a; a.u = ((unsigned)u) << 16;
  return a.f;
}

// ---------------- converts ----------------
__global__ __launch_bounds__(256) void conv_bf16(const float* __restrict__ in,
                                                 u16* __restrict__ out, int n4) {
  int i = blockIdx.x * 256 + threadIdx.x;
  if (i >= n4) return;
  const float4 v = *(const float4*)(in + (size_t)i * 4);
  ushort4 o;
  o.x = f2b(v.x); o.y = f2b(v.y); o.z = f2b(v.z); o.w = f2b(v.w);
  *(ushort4*)(out + (size_t)i * 4) = o;
}

// k_cache [16][1536][64] f32 -> k_full [16][2048][64] bf16 (rows 0..1535)
__global__ __launch_bounds__(256) void kcache_copy(const float* __restrict__ kc,
                                                   u16* __restrict__ kf) {
  int i = blockIdx.x * 256 + threadIdx.x;  // 393216 chunks of 4
  int bh = i / 24576, r = i - bh * 24576;
  const float4 v = *(const float4*)(kc + (size_t)bh * 98304 + (size_t)r * 4);
  ushort4 o;
  o.x = f2b(v.x); o.y = f2b(v.y); o.z = f2b(v.z); o.w = f2b(v.w);
  *(ushort4*)(kf + (size_t)bh * 131072 + (size_t)r * 4) = o;
}

// v_cache [16][1536][64] f32 -> vT [16][64][2048] bf16 (cols 0..1535), LDS-tiled transpose
__global__ __launch_bounds__(256) void vcache_transpose(const float* __restrict__ vc,
                                                        u16* __restrict__ vT) {
  __shared__ float tile[64][65];
  const int bh = blockIdx.y, kt = blockIdx.x;
  const float* src = vc + ((size_t)bh * 1536 + (size_t)kt * 64) * 64;
  const int t = threadIdx.x;
#pragma unroll
  for (int j = 0; j < 4; j++) {
    int e = t + j * 256;            // 0..1023 chunks of 4
    int r = e >> 4, c = (e & 15) * 4;
    float4 v = *(const float4*)(src + (size_t)r * 64 + c);
    tile[r][c] = v.x; tile[r][c + 1] = v.y; tile[r][c + 2] = v.z; tile[r][c + 3] = v.w;
  }
  __syncthreads();
  int d = t >> 2, kv0 = (t & 3) * 16;
  u16* dst = vT + ((size_t)bh * 64 + d) * 2048 + (size_t)kt * 64 + kv0;
#pragma unroll
  for (int i = 0; i < 16; i++) dst[i] = f2b(tile[kv0 + i][d]);
}

// ---------------- GEMM: C[M][N] = A[M][K] * B[N][K]^T  (bf16 in, f32 out) ----------------
__global__ __launch_bounds__(256) void gemm_bt(const u16* __restrict__ A,
                                               const u16* __restrict__ B,
                                               float* __restrict__ C,
                                               int M, int N, int K) {
  __shared__ __attribute__((aligned(16))) u16 As[4096];  // 128 x 32
  __shared__ __attribute__((aligned(16))) u16 Bs[4096];
  const int t = threadIdx.x;
  const int lane = t & 63, wv = t >> 6;
  const int wr = (wv >> 1) * 64, wc = (wv & 1) * 64;
  const int g = lane >> 4, cc = lane & 15;
  const size_t row0 = (size_t)blockIdx.x * 128, col0 = (size_t)blockIdx.y * 128;

  f32x4 acc[4][4] = {};

  const int sr = t >> 2, sce = (t & 3) * 8;
  const u16* a0 = A + (row0 + sr) * K + sce;
  const u16* a1 = A + (row0 + 64 + sr) * K + sce;
  const u16* b0 = B + (col0 + sr) * K + sce;
  const u16* b1 = B + (col0 + 64 + sr) * K + sce;
  u16* ldsA0 = As + wv * 512;
  u16* ldsA1 = As + 2048 + wv * 512;
  u16* ldsB0 = Bs + wv * 512;
  u16* ldsB1 = Bs + 2048 + wv * 512;

  for (int k0 = 0; k0 < K; k0 += 32) {
    __syncthreads();
    __builtin_amdgcn_global_load_lds((const __attribute__((address_space(1))) void*)(a0 + k0),
                                     (__attribute__((address_space(3))) void*)ldsA0, 16, 0, 0);
    __builtin_amdgcn_global_load_lds((const __attribute__((address_space(1))) void*)(a1 + k0),
                                     (__attribute__((address_space(3))) void*)ldsA1, 16, 0, 0);
    __builtin_amdgcn_global_load_lds((const __attribute__((address_space(1))) void*)(b0 + k0),
                                     (__attribute__((address_space(3))) void*)ldsB0, 16, 0, 0);
    __builtin_amdgcn_global_load_lds((const __attribute__((address_space(1))) void*)(b1 + k0),
                                     (__attribute__((address_space(3))) void*)ldsB1, 16, 0, 0);
    __syncthreads();
    bf16x8 av[4], bv[4];
#pragma unroll
    for (int m = 0; m < 4; m++)
      av[m] = *(const bf16x8*)(As + (wr + m * 16 + cc) * 32 + g * 8);
#pragma unroll
    for (int n = 0; n < 4; n++)
      bv[n] = *(const bf16x8*)(Bs + (wc + n * 16 + cc) * 32 + g * 8);
#pragma unroll
    for (int m = 0; m < 4; m++)
#pragma unroll
      for (int n = 0; n < 4; n++)
        acc[m][n] = MFMA16(av[m], bv[n], acc[m][n]);
  }
#pragma unroll
  for (int m = 0; m < 4; m++)
#pragma unroll
    for (int n = 0; n < 4; n++)
#pragma unroll
      for (int r = 0; r < 4; r++)
        C[(row0 + wr + m * 16 + g * 4 + r) * N + (col0 + wc + n * 16 + cc)] = acc[m][n][r];
}

// ---------------- RoPE + scatter ----------------
// Cqkv [1024][3072] f32. q cols 0..2047, k cols 2048..2559, v cols 2560..3071
__global__ __launch_bounds__(256) void postproc(const float* __restrict__ Cqkv,
                                                const float* __restrict__ fcos,
                                                const float* __restrict__ fsin,
                                                u16* __restrict__ qrope,
                                                u16* __restrict__ kfull,
                                                u16* __restrict__ vT,
                                                float* __restrict__ newk,
                                                float* __restrict__ newv) {
  int idx = blockIdx.x * 256 + threadIdx.x;
  if (idx >= 1024 * 1536) return;
  int m = idx / 1536, p = idx - m * 1536;
  int b = m >> 9, s = m & 511;
  const float* row = Cqkv + (size_t)m * 3072;
  if (p < 1280) {
    bool isq = p < 1024;
    int pk = isq ? p : p - 1024;
    int h = pk >> 5, i = pk & 31;
    int colbase = (isq ? 0 : 2048) + h * 64 + 2 * i;
    float xr = row[colbase], xi = row[colbase + 1];
    float co = fcos[s * 32 + i], si = fsin[s * 32 + i];
    float orr = xr * co - xi * si;
    float oii = xr * si + xi * co;
    if (isq) {
      u16* dst = qrope + (((size_t)(b * 32 + h) * 512 + s) * 64 + 2 * i);
      dst[0] = f2b(orr); dst[1] = f2b(oii);
    } else {
      size_t o0 = ((size_t)(b * 8 + h) * 512 + s) * 64 + 2 * i;
      newk[o0] = orr; newk[o0 + 1] = oii;
      u16* kf = kfull + (((size_t)(b * 8 + h) * 2048 + 1536 + s) * 64 + 2 * i);
      kf[0] = f2b(orr); kf[1] = f2b(oii);
    }
  } else {
    int pv = p - 1280;
    int h = pv >> 5, i = pv & 31;
    float v0 = row[2560 + h * 64 + 2 * i], v1 = row[2560 + h * 64 + 2 * i + 1];
    size_t o0 = ((size_t)(b * 8 + h) * 512 + s) * 64 + 2 * i;
    newv[o0] = v0; newv[o0 + 1] = v1;
    u16* vt = vT + ((size_t)(b * 8 + h) * 64 + 2 * i) * 2048 + 1536 + s;
    vt[0] = f2b(v0); vt[2048] = f2b(v1);
  }
}

// ---------------- flash attention, KV-split 2-way ----------------
// qrope [64bh][512][64] bf16, kfull [16bhkv][2048][64] bf16, vT [16bhkv][64][2048] bf16,
// maskb [512][2048] bf16.
// po [bh*512+s][sp][64] f32 (unnormalized), ml [bh*512+s][sp] float2 (m, l)
__global__ __launch_bounds__(256, 4) void attn_split(const u16* __restrict__ qrope,
                                                     const u16* __restrict__ kfull,
                                                     const u16* __restrict__ vT,
                                                     const u16* __restrict__ maskb,
                                                     float* __restrict__ po,
                                                     float* __restrict__ ml) {
  __shared__ __attribute__((aligned(16))) u16 P_lds[4096];  // 4 waves x 16x64
  const int t = threadIdx.x, lane = t & 63, w = t >> 6;
  const int g = lane >> 4, cc = lane & 15;
  // XCD-bijective swizzle: 1024 blocks -> 8 chunks of 128 (8 bh per XCD)
  const int p = blockIdx.x;
  const int v = (p & 7) * 128 + (p >> 3);
  const int bh = v >> 4, qt = (v >> 1) & 7, sp = v & 1;
  const int b = bh >> 5, h = bh & 31;
  const int bhkv = b * 8 + (h >> 2);
  const int s0 = qt * 64 + w * 16;
  const int j0beg = sp * 1024;

  bf16x8 qa0, qa1;
  {
    const u16* qb = qrope + ((size_t)bh * 512 + s0 + cc) * 64 + g * 8;
    qa0 = *(const bf16x8*)qb;
    qa1 = *(const bf16x8*)(qb + 32);
  }
  float mrow[4], ssum[4];
  f32x4 o[4] = {};
#pragma unroll
  for (int r = 0; r < 4; r++) { mrow[r] = -1e30f; ssum[r] = 0.0f; }

  u16* Pw = P_lds + w * 1024;
  const u16* kbase = kfull + ((size_t)bhkv * 2048 + cc) * 64 + g * 8;
  const u16* vbase = vT + ((size_t)bhkv * 64 + cc) * 2048 + g * 8;
  const u16* mbase = maskb + (size_t)(s0 + g * 4) * 2048 + cc;

  for (int j0 = j0beg; j0 < j0beg + 1024; j0 += 64) {
    // issue all K fragments (independent)
    bf16x8 kf[4][2];
#pragma unroll
    for (int jb = 0; jb < 4; jb++) {
      const u16* kp = kbase + (size_t)(j0 + jb * 16) * 64;
      kf[jb][0] = *(const bf16x8*)kp;
      kf[jb][1] = *(const bf16x8*)(kp + 32);
    }
    // issue all V fragments early (independent of QK/softmax)
    bf16x8 vb[2][4];
#pragma unroll
    for (int kk = 0; kk < 2; kk++)
#pragma unroll
      for (int db = 0; db < 4; db++)
        vb[kk][db] = *(const bf16x8*)(vbase + (size_t)(db * 16) * 2048 + j0 + kk * 32);
    // mask (bf16)
    float mk[4][4];
#pragma unroll
    for (int r = 0; r < 4; r++)
#pragma unroll
      for (int jb = 0; jb < 4; jb++)
        mk[r][jb] = b2f(mbase[(size_t)r * 2048 + j0 + jb * 16]);

    f32x4 sc[4];
#pragma unroll
    for (int jb = 0; jb < 4; jb++) {
      f32x4 z = {0.f, 0.f, 0.f, 0.f};
      z = MFMA16(qa0, kf[jb][0], z);
      z = MFMA16(qa1, kf[jb][1], z);
      sc[jb] = z;
    }
    float pp[4][4];
#pragma unroll
    for (int r = 0; r < 4; r++) {
#pragma unroll
      for (int jb = 0; jb < 4; jb++)
        pp[r][jb] = sc[jb][r] * 0.125f + mk[r][jb];
      float tm = fmaxf(fmaxf(pp[r][0], pp[r][1]), fmaxf(pp[r][2], pp[r][3]));
#pragma unroll
      for (int off = 1; off < 16; off <<= 1) tm = fmaxf(tm, __shfl_xor(tm, off, 64));
      float newm = fmaxf(mrow[r], tm);
      float corr = __expf(mrow[r] - newm);
      mrow[r] = newm;
      float ps = 0.f;
#pragma unroll
      for (int jb = 0; jb < 4; jb++) { pp[r][jb] = __expf(pp[r][jb] - newm); ps += pp[r][jb]; }
#pragma unroll
      for (int off = 1; off < 16; off <<= 1) ps += __shfl_xor(ps, off, 64);
      ssum[r] = ssum[r] * corr + ps;
#pragma unroll
      for (int db = 0; db < 4; db++) o[db][r] *= corr;
      const int rowb = (g * 4 + r) * 128;
      const int sw = ((g * 4 + r) & 7) << 4;
#pragma unroll
      for (int jb = 0; jb < 4; jb++)
        Pw[((rowb + (jb * 16 + cc) * 2) ^ sw) >> 1] = f2b(pp[r][jb]);
    }
#pragma unroll
    for (int kk = 0; kk < 2; kk++) {
      const bf16x8 pa =
          *(const bf16x8*)(Pw + (((cc * 128 + kk * 64 + g * 16) ^ ((cc & 7) << 4)) >> 1));
#pragma unroll
      for (int db = 0; db < 4; db++)
        o[db] = MFMA16(pa, vb[kk][db], o[db]);
    }
  }
  // write partials: po[(row*2+sp)*64 + d], ml[(row*2+sp)] = (m, l)
#pragma unroll
  for (int r = 0; r < 4; r++) {
    const size_t row = (size_t)bh * 512 + s0 + g * 4 + r;
    float* dst = po + (row * 2 + sp) * 64 + cc;
#pragma unroll
    for (int db = 0; db < 4; db++) dst[db * 16] = o[db][r];
    if (cc == 0) {
      float2* mlp = (float2*)ml;
      mlp[row * 2 + sp] = make_float2(mrow[r], ssum[r]);
    }
  }
}

// combine 2 splits -> aout bf16 [1024][2048] (b,s, h*64+d)
__global__ __launch_bounds__(256) void attn_combine(const float* __restrict__ po,
                                                    const float* __restrict__ ml,
                                                    u16* __restrict__ aout) {
  const int t = threadIdx.x;
  const int row = blockIdx.x * 4 + (t >> 6);  // bh*512 + s
  const int d = t & 63;
  const int bh = row >> 9, s = row & 511;
  const int b = bh >> 5, h = bh & 31;
  const float2* mlp = (const float2*)ml;
  const float2 m0 = mlp[row * 2 + 0], m1 = mlp[row * 2 + 1];
  const float M = fmaxf(m0.x, m1.x);
  const float w0 = __expf(m0.x - M), w1 = __expf(m1.x - M);
  const float L = m0.y * w0 + m1.y * w1;
  const float o = po[(size_t)(row * 2 + 0) * 64 + d] * w0 +
                  po[(size_t)(row * 2 + 1) * 64 + d] * w1;
  aout[((size_t)(b * 512 + s)) * 2048 + h * 64 + d] = f2b(o / L);
}

// ---------------- launch ----------------
extern "C" void kernel_launch(void* const* d_in, const int* in_sizes, int n_in,
                              void* d_out, int out_size, void* d_ws, size_t ws_size,
                              hipStream_t stream) {
  (void)in_sizes; (void)n_in; (void)out_size; (void)ws_size;
  const float* x    = (const float*)d_in[0];
  const float* fcos = (const float*)d_in[1];
  const float* fsin = (const float*)d_in[2];
  const float* kc   = (const float*)d_in[3];
  const float* vc   = (const float*)d_in[4];
  const float* mask = (const float*)d_in[5];
  const float* wq   = (const float*)d_in[6];
  const float* wk   = (const float*)d_in[7];
  const float* wv   = (const float*)d_in[8];
  const float* wo   = (const float*)d_in[9];

  float* out_f = (float*)d_out;                 // [2][512][2048]
  float* newk  = out_f + 2097152;               // [2][8][512][64]
  float* newv  = out_f + 2621440;               // [2][8][512][64]

  u16*   xb    = (u16*)d_ws;                    // 4MB   (dead after gemm1)
  u16*   wcat  = xb + 2097152;                  // 12MB  (dead after gemm1)
  u16*   wob   = wcat + 6291456;                // 8MB   (live until gemm2)
  float* Cqkv  = (float*)(wob + 4194304);       // 12MB  (dead after postproc)
  u16*   qrope = (u16*)(Cqkv + 3145728);        // 4MB
  u16*   kfull = qrope + 2097152;               // 4MB
  u16*   vTf   = kfull + 2097152;               // 4MB
  u16*   aout  = vTf + 2097152;                 // 4MB
  // aliases (live only during attention phase):
  float* po    = (float*)d_ws;                  // 16MB over xb+wcat
  float* ml    = Cqkv;                          // 0.5MB over Cqkv
  u16*   maskb = (u16*)(Cqkv + 131072);         // 2MB over Cqkv+0.5MB

  conv_bf16<<<2048, 256, 0, stream>>>(x, xb, 524288);
  conv_bf16<<<4096, 256, 0, stream>>>(wq, wcat, 1048576);
  conv_bf16<<<1024, 256, 0, stream>>>(wk, wcat + 4194304, 262144);
  conv_bf16<<<1024, 256, 0, stream>>>(wv, wcat + 5242880, 262144);
  conv_bf16<<<4096, 256, 0, stream>>>(wo, wob, 1048576);
  kcache_copy<<<1536, 256, 0, stream>>>(kc, kfull);
  vcache_transpose<<<dim3(24, 16), 256, 0, stream>>>(vc, vTf);

  gemm_bt<<<dim3(8, 24), 256, 0, stream>>>(xb, wcat, Cqkv, 1024, 3072, 2048);
  postproc<<<6144, 256, 0, stream>>>(Cqkv, fcos, fsin, qrope, kfull, vTf, newk, newv);
  conv_bf16<<<1024, 256, 0, stream>>>(mask, maskb, 262144);   // after postproc (aliases Cqkv)
  attn_split<<<1024, 256, 0, stream>>>(qrope, kfull, vTf, maskb, po, ml);
  attn_combine<<<8192, 256, 0, stream>>>(po, ml, aout);
  gemm_bt<<<dim3(8, 16), 256, 0, stream>>>(aout, wob, out_f, 1024, 2048, 2048);
}

// Round 6
// 204.435 us; speedup vs baseline: 1.3591x; 1.3591x over previous
//
#include <hip/hip_runtime.h>

typedef __attribute__((ext_vector_type(8))) short bf16x8;
typedef __attribute__((ext_vector_type(4))) float f32x4;
typedef unsigned short u16;

#define MFMA16(a, b, c) __builtin_amdgcn_mfma_f32_16x16x32_bf16(a, b, c, 0, 0, 0)
#define GLL(srcp, dstp) __builtin_amdgcn_global_load_lds(                      \
    (const __attribute__((address_space(1))) void*)(srcp),                     \
    (__attribute__((address_space(3))) void*)(dstp), 16, 0, 0)

__device__ __forceinline__ u16 f2b(float f) {
  union { float f; unsigned u; } a; a.f = f;
  return (u16)((a.u + 0x7FFFu + ((a.u >> 16) & 1u)) >> 16);
}
__device__ __forceinline__ float b2f(u16 u) {
  union { unsigned u; float f; } a; a.u = ((unsigned)u) << 16;
  return a.f;
}

// ---------------- converts ----------------
__global__ __launch_bounds__(256) void conv_bf16(const float* __restrict__ in,
                                                 u16* __restrict__ out, int n4) {
  int i = blockIdx.x * 256 + threadIdx.x;
  if (i >= n4) return;
  const float4 v = *(const float4*)(in + (size_t)i * 4);
  ushort4 o;
  o.x = f2b(v.x); o.y = f2b(v.y); o.z = f2b(v.z); o.w = f2b(v.w);
  *(ushort4*)(out + (size_t)i * 4) = o;
}

// k_cache [16][1536][64] f32 -> k_full [16][2048][64] bf16 (rows 0..1535)
__global__ __launch_bounds__(256) void kcache_copy(const float* __restrict__ kc,
                                                   u16* __restrict__ kf) {
  int i = blockIdx.x * 256 + threadIdx.x;  // 393216 chunks of 4
  int bh = i / 24576, r = i - bh * 24576;
  const float4 v = *(const float4*)(kc + (size_t)bh * 98304 + (size_t)r * 4);
  ushort4 o;
  o.x = f2b(v.x); o.y = f2b(v.y); o.z = f2b(v.z); o.w = f2b(v.w);
  *(ushort4*)(kf + (size_t)bh * 131072 + (size_t)r * 4) = o;
}

// v_cache [16][1536][64] f32 -> vT [16][64][2048] bf16 (cols 0..1535), LDS-tiled transpose
__global__ __launch_bounds__(256) void vcache_transpose(const float* __restrict__ vc,
                                                        u16* __restrict__ vT) {
  __shared__ float tile[64][65];
  const int bh = blockIdx.y, kt = blockIdx.x;
  const float* src = vc + ((size_t)bh * 1536 + (size_t)kt * 64) * 64;
  const int t = threadIdx.x;
#pragma unroll
  for (int j = 0; j < 4; j++) {
    int e = t + j * 256;            // 0..1023 chunks of 4
    int r = e >> 4, c = (e & 15) * 4;
    float4 v = *(const float4*)(src + (size_t)r * 64 + c);
    tile[r][c] = v.x; tile[r][c + 1] = v.y; tile[r][c + 2] = v.z; tile[r][c + 3] = v.w;
  }
  __syncthreads();
  int d = t >> 2, kv0 = (t & 3) * 16;
  u16* dst = vT + ((size_t)bh * 64 + d) * 2048 + (size_t)kt * 64 + kv0;
#pragma unroll
  for (int i = 0; i < 16; i++) dst[i] = f2b(tile[kv0 + i][d]);
}

// ---------------- GEMM: C[M][N] = A[M][K] * B[N][K]^T  (bf16 in, f32 out) ----------------
__global__ __launch_bounds__(256) void gemm_bt(const u16* __restrict__ A,
                                               const u16* __restrict__ B,
                                               float* __restrict__ C,
                                               int M, int N, int K) {
  __shared__ __attribute__((aligned(16))) u16 As[4096];  // 128 x 32
  __shared__ __attribute__((aligned(16))) u16 Bs[4096];
  const int t = threadIdx.x;
  const int lane = t & 63, wv = t >> 6;
  const int wr = (wv >> 1) * 64, wc = (wv & 1) * 64;
  const int g = lane >> 4, cc = lane & 15;
  const size_t row0 = (size_t)blockIdx.x * 128, col0 = (size_t)blockIdx.y * 128;

  f32x4 acc[4][4] = {};

  const int sr = t >> 2, sce = (t & 3) * 8;
  const u16* a0 = A + (row0 + sr) * K + sce;
  const u16* a1 = A + (row0 + 64 + sr) * K + sce;
  const u16* b0 = B + (col0 + sr) * K + sce;
  const u16* b1 = B + (col0 + 64 + sr) * K + sce;
  u16* ldsA0 = As + wv * 512;
  u16* ldsA1 = As + 2048 + wv * 512;
  u16* ldsB0 = Bs + wv * 512;
  u16* ldsB1 = Bs + 2048 + wv * 512;

  for (int k0 = 0; k0 < K; k0 += 32) {
    __syncthreads();
    GLL(a0 + k0, ldsA0);
    GLL(a1 + k0, ldsA1);
    GLL(b0 + k0, ldsB0);
    GLL(b1 + k0, ldsB1);
    __syncthreads();
    bf16x8 av[4], bv[4];
#pragma unroll
    for (int m = 0; m < 4; m++)
      av[m] = *(const bf16x8*)(As + (wr + m * 16 + cc) * 32 + g * 8);
#pragma unroll
    for (int n = 0; n < 4; n++)
      bv[n] = *(const bf16x8*)(Bs + (wc + n * 16 + cc) * 32 + g * 8);
#pragma unroll
    for (int m = 0; m < 4; m++)
#pragma unroll
      for (int n = 0; n < 4; n++)
        acc[m][n] = MFMA16(av[m], bv[n], acc[m][n]);
  }
#pragma unroll
  for (int m = 0; m < 4; m++)
#pragma unroll
    for (int n = 0; n < 4; n++)
#pragma unroll
      for (int r = 0; r < 4; r++)
        C[(row0 + wr + m * 16 + g * 4 + r) * N + (col0 + wc + n * 16 + cc)] = acc[m][n][r];
}

// ---------------- RoPE + scatter ----------------
// Cqkv [1024][3072] f32. q cols 0..2047, k cols 2048..2559, v cols 2560..3071
__global__ __launch_bounds__(256) void postproc(const float* __restrict__ Cqkv,
                                                const float* __restrict__ fcos,
                                                const float* __restrict__ fsin,
                                                u16* __restrict__ qrope,
                                                u16* __restrict__ kfull,
                                                u16* __restrict__ vT,
                                                float* __restrict__ newk,
                                                float* __restrict__ newv) {
  int idx = blockIdx.x * 256 + threadIdx.x;
  if (idx >= 1024 * 1536) return;
  int m = idx / 1536, p = idx - m * 1536;
  int b = m >> 9, s = m & 511;
  const float* row = Cqkv + (size_t)m * 3072;
  if (p < 1280) {
    bool isq = p < 1024;
    int pk = isq ? p : p - 1024;
    int h = pk >> 5, i = pk & 31;
    int colbase = (isq ? 0 : 2048) + h * 64 + 2 * i;
    float xr = row[colbase], xi = row[colbase + 1];
    float co = fcos[s * 32 + i], si = fsin[s * 32 + i];
    float orr = xr * co - xi * si;
    float oii = xr * si + xi * co;
    if (isq) {
      u16* dst = qrope + (((size_t)(b * 32 + h) * 512 + s) * 64 + 2 * i);
      dst[0] = f2b(orr); dst[1] = f2b(oii);
    } else {
      size_t o0 = ((size_t)(b * 8 + h) * 512 + s) * 64 + 2 * i;
      newk[o0] = orr; newk[o0 + 1] = oii;
      u16* kf = kfull + (((size_t)(b * 8 + h) * 2048 + 1536 + s) * 64 + 2 * i);
      kf[0] = f2b(orr); kf[1] = f2b(oii);
    }
  } else {
    int pv = p - 1280;
    int h = pv >> 5, i = pv & 31;
    float v0 = row[2560 + h * 64 + 2 * i], v1 = row[2560 + h * 64 + 2 * i + 1];
    size_t o0 = ((size_t)(b * 8 + h) * 512 + s) * 64 + 2 * i;
    newv[o0] = v0; newv[o0 + 1] = v1;
    u16* vt = vT + ((size_t)(b * 8 + h) * 64 + 2 * i) * 2048 + 1536 + s;
    vt[0] = f2b(v0); vt[2048] = f2b(v1);
  }
}

// ---------------- flash attention, KV-split 2-way, LDS-staged K/V ----------------
// qrope [64bh][512][64] bf16, kfull [16bhkv][2048][64] bf16, vT [16bhkv][64][2048] bf16,
// mask [512][2048] f32.
// po [bh*512+s][sp][64] f32 (unnormalized), ml [bh*512+s][sp] float2 (m, l)
// LDS tiles hold 16B granules swizzled: LDS(row, c) = Global(row, c ^ (row&7)).
__global__ __launch_bounds__(256, 4) void attn_split(const u16* __restrict__ qrope,
                                                     const u16* __restrict__ kfull,
                                                     const u16* __restrict__ vT,
                                                     const float* __restrict__ mask,
                                                     float* __restrict__ po,
                                                     float* __restrict__ ml) {
  __shared__ __attribute__((aligned(16))) u16 Ks[2][4096];  // [buf][64 kv][64 d]
  __shared__ __attribute__((aligned(16))) u16 Vs[2][4096];  // [buf][64 d][64 kv]
  __shared__ __attribute__((aligned(16))) u16 P_lds[4096];  // 4 waves x 16x64
  const int t = threadIdx.x, lane = t & 63, w = t >> 6;
  const int g = lane >> 4, cc = lane & 15;
  // XCD-bijective swizzle: 1024 blocks -> 8 chunks of 128 (8 bh per XCD)
  const int p = blockIdx.x;
  const int v = (p & 7) * 128 + (p >> 3);
  const int bh = v >> 4, qt = (v >> 1) & 7, sp = v & 1;
  const int b = bh >> 5, h = bh & 31;
  const int bhkv = b * 8 + (h >> 2);
  const int s0 = qt * 64 + w * 16;
  const int j0beg = sp * 1024;

  // staging lane geometry: 16B granules; local row lr (8 granules/row), col lc
  const int lr = lane >> 3, lc = lane & 7;
  const int swzc = lc ^ lr;  // pre-swizzled source granule column

  bf16x8 qa0, qa1;
  {
    const u16* qb = qrope + ((size_t)bh * 512 + s0 + cc) * 64 + g * 8;
    qa0 = *(const bf16x8*)qb;
    qa1 = *(const bf16x8*)(qb + 32);
  }
  float mrow[4], ssum[4];
  f32x4 o[4] = {};
#pragma unroll
  for (int r = 0; r < 4; r++) { mrow[r] = -1e30f; ssum[r] = 0.0f; }

  u16* Pw = P_lds + w * 1024;
  const float* mbase = mask + (size_t)(s0 + g * 4) * 2048 + cc;
  // per-wave staging sources (element offsets added per tile)
  const u16* ksrc0 = kfull + (size_t)bhkv * 131072 + (size_t)(w * 16 + lr) * 64 + swzc * 8;
  const u16* vsrc0 = vT + ((size_t)bhkv * 64 + w * 16 + lr) * 2048 + swzc * 8;

  // prologue: stage tile 0 into buf 0
  {
    const u16* ks = ksrc0 + (size_t)j0beg * 64;
    const u16* vs = vsrc0 + j0beg;
    GLL(ks, &Ks[0][w * 1024]);
    GLL(ks + 8 * 64, &Ks[0][w * 1024 + 512]);
    GLL(vs, &Vs[0][w * 1024]);
    GLL(vs + 8 * 2048, &Vs[0][w * 1024 + 512]);
  }
  __syncthreads();

  for (int it = 0; it < 16; ++it) {
    const int buf = it & 1;
    const int j0 = j0beg + it * 64;
    if (it < 15) {  // stage next tile into buf^1 (overlaps with compute below)
      const u16* ks = ksrc0 + (size_t)(j0 + 64) * 64;
      const u16* vs = vsrc0 + (j0 + 64);
      GLL(ks, &Ks[buf ^ 1][w * 1024]);
      GLL(ks + 8 * 64, &Ks[buf ^ 1][w * 1024 + 512]);
      GLL(vs, &Vs[buf ^ 1][w * 1024]);
      GLL(vs + 8 * 2048, &Vs[buf ^ 1][w * 1024 + 512]);
    }

    // QK^T from LDS (swizzled reads)
    f32x4 sc[4];
#pragma unroll
    for (int jb = 0; jb < 4; jb++) {
      const bf16x8 k0 = *(const bf16x8*)(&Ks[buf][(jb * 16 + cc) * 64 + ((g ^ (cc & 7)) * 8)]);
      const bf16x8 k1 =
          *(const bf16x8*)(&Ks[buf][(jb * 16 + cc) * 64 + (((g + 4) ^ (cc & 7)) * 8)]);
      f32x4 z = {0.f, 0.f, 0.f, 0.f};
      z = MFMA16(qa0, k0, z);
      z = MFMA16(qa1, k1, z);
      sc[jb] = z;
    }
    // softmax (online), mask f32 direct
    float pp[4][4];
#pragma unroll
    for (int r = 0; r < 4; r++) {
#pragma unroll
      for (int jb = 0; jb < 4; jb++)
        pp[r][jb] = sc[jb][r] * 0.125f + mbase[(size_t)r * 2048 + j0 + jb * 16];
      float tm = fmaxf(fmaxf(pp[r][0], pp[r][1]), fmaxf(pp[r][2], pp[r][3]));
#pragma unroll
      for (int off = 1; off < 16; off <<= 1) tm = fmaxf(tm, __shfl_xor(tm, off, 64));
      float newm = fmaxf(mrow[r], tm);
      float corr = __expf(mrow[r] - newm);
      mrow[r] = newm;
      float ps = 0.f;
#pragma unroll
      for (int jb = 0; jb < 4; jb++) { pp[r][jb] = __expf(pp[r][jb] - newm); ps += pp[r][jb]; }
#pragma unroll
      for (int off = 1; off < 16; off <<= 1) ps += __shfl_xor(ps, off, 64);
      ssum[r] = ssum[r] * corr + ps;
#pragma unroll
      for (int db = 0; db < 4; db++) o[db][r] *= corr;
      const int rowb = (g * 4 + r) * 128;
      const int sw = ((g * 4 + r) & 7) << 4;
#pragma unroll
      for (int jb = 0; jb < 4; jb++)
        Pw[((rowb + (jb * 16 + cc) * 2) ^ sw) >> 1] = f2b(pp[r][jb]);
    }
    // PV from LDS V (swizzled reads)
#pragma unroll
    for (int kk = 0; kk < 2; kk++) {
      const bf16x8 pa =
          *(const bf16x8*)(Pw + (((cc * 128 + kk * 64 + g * 16) ^ ((cc & 7) << 4)) >> 1));
#pragma unroll
      for (int db = 0; db < 4; db++) {
        const bf16x8 vf =
            *(const bf16x8*)(&Vs[buf][(db * 16 + cc) * 64 + (((kk * 4 + g) ^ (cc & 7)) * 8)]);
        o[db] = MFMA16(pa, vf, o[db]);
      }
    }
    __syncthreads();  // drains staging loads (vmcnt 0) + protects buf reuse
  }
  // write partials: po[(row*2+sp)*64 + d], ml[(row*2+sp)] = (m, l)
#pragma unroll
  for (int r = 0; r < 4; r++) {
    const size_t row = (size_t)bh * 512 + s0 + g * 4 + r;
    float* dst = po + (row * 2 + sp) * 64 + cc;
#pragma unroll
    for (int db = 0; db < 4; db++) dst[db * 16] = o[db][r];
    if (cc == 0) {
      float2* mlp = (float2*)ml;
      mlp[row * 2 + sp] = make_float2(mrow[r], ssum[r]);
    }
  }
}

// combine 2 splits -> aout bf16 [1024][2048] (b,s, h*64+d)
__global__ __launch_bounds__(256) void attn_combine(const float* __restrict__ po,
                                                    const float* __restrict__ ml,
                                                    u16* __restrict__ aout) {
  const int t = threadIdx.x;
  const int row = blockIdx.x * 4 + (t >> 6);  // bh*512 + s
  const int d = t & 63;
  const int bh = row >> 9, s = row & 511;
  const int b = bh >> 5, h = bh & 31;
  const float2* mlp = (const float2*)ml;
  const float2 m0 = mlp[row * 2 + 0], m1 = mlp[row * 2 + 1];
  const float M = fmaxf(m0.x, m1.x);
  const float w0 = __expf(m0.x - M), w1 = __expf(m1.x - M);
  const float L = m0.y * w0 + m1.y * w1;
  const float o = po[(size_t)(row * 2 + 0) * 64 + d] * w0 +
                  po[(size_t)(row * 2 + 1) * 64 + d] * w1;
  aout[((size_t)(b * 512 + s)) * 2048 + h * 64 + d] = f2b(o / L);
}

// ---------------- launch ----------------
extern "C" void kernel_launch(void* const* d_in, const int* in_sizes, int n_in,
                              void* d_out, int out_size, void* d_ws, size_t ws_size,
                              hipStream_t stream) {
  (void)in_sizes; (void)n_in; (void)out_size; (void)ws_size;
  const float* x    = (const float*)d_in[0];
  const float* fcos = (const float*)d_in[1];
  const float* fsin = (const float*)d_in[2];
  const float* kc   = (const float*)d_in[3];
  const float* vc   = (const float*)d_in[4];
  const float* mask = (const float*)d_in[5];
  const float* wq   = (const float*)d_in[6];
  const float* wk   = (const float*)d_in[7];
  const float* wv   = (const float*)d_in[8];
  const float* wo   = (const float*)d_in[9];

  float* out_f = (float*)d_out;                 // [2][512][2048]
  float* newk  = out_f + 2097152;               // [2][8][512][64]
  float* newv  = out_f + 2621440;               // [2][8][512][64]

  u16*   xb    = (u16*)d_ws;                    // 4MB   (dead after gemm1)
  u16*   wcat  = xb + 2097152;                  // 12MB  (dead after gemm1)
  u16*   wob   = wcat + 6291456;                // 8MB   (live until gemm2)
  float* Cqkv  = (float*)(wob + 4194304);       // 12MB  (dead after postproc)
  u16*   qrope = (u16*)(Cqkv + 3145728);        // 4MB
  u16*   kfull = qrope + 2097152;               // 4MB
  u16*   vTf   = kfull + 2097152;               // 4MB
  u16*   aout  = vTf + 2097152;                 // 4MB
  // aliases (live only during attention phase):
  float* po    = (float*)d_ws;                  // 16MB over xb+wcat
  float* ml    = Cqkv;                          // 0.5MB over Cqkv (dead after postproc)

  conv_bf16<<<2048, 256, 0, stream>>>(x, xb, 524288);
  conv_bf16<<<4096, 256, 0, stream>>>(wq, wcat, 1048576);
  conv_bf16<<<1024, 256, 0, stream>>>(wk, wcat + 4194304, 262144);
  conv_bf16<<<1024, 256, 0, stream>>>(wv, wcat + 5242880, 262144);
  conv_bf16<<<4096, 256, 0, stream>>>(wo, wob, 1048576);
  kcache_copy<<<1536, 256, 0, stream>>>(kc, kfull);
  vcache_transpose<<<dim3(24, 16), 256, 0, stream>>>(vc, vTf);

  gemm_bt<<<dim3(8, 24), 256, 0, stream>>>(xb, wcat, Cqkv, 1024, 3072, 2048);
  postproc<<<6144, 256, 0, stream>>>(Cqkv, fcos, fsin, qrope, kfull, vTf, newk, newv);
  attn_split<<<1024, 256, 0, stream>>>(qrope, kfull, vTf, mask, po, ml);
  attn_combine<<<8192, 256, 0, stream>>>(po, ml, aout);
  gemm_bt<<<dim3(8, 16), 256, 0, stream>>>(aout, wob, out_f, 1024, 2048, 2048);
}

// Round 7
// 167.431 us; speedup vs baseline: 1.6595x; 1.2210x over previous
//
#include <hip/hip_runtime.h>

typedef __attribute__((ext_vector_type(8))) short bf16x8;
typedef __attribute__((ext_vector_type(4))) float f32x4;
typedef unsigned short u16;

#define MFMA16(a, b, c) __builtin_amdgcn_mfma_f32_16x16x32_bf16(a, b, c, 0, 0, 0)
#define GLL(srcp, dstp) __builtin_amdgcn_global_load_lds(                      \
    (const __attribute__((address_space(1))) void*)(srcp),                     \
    (__attribute__((address_space(3))) void*)(dstp), 16, 0, 0)

__device__ __forceinline__ u16 f2b(float f) {
  union { float f; unsigned u; } a; a.f = f;
  return (u16)((a.u + 0x7FFFu + ((a.u >> 16) & 1u)) >> 16);
}

// ---------------- fused prep: f32->bf16 converts + k_cache copy ----------------
// segments in 4-elem chunks:
// x:      [0,        524288)   -> xb
// wq:     [524288,   1572864)  -> wcat
// wk:     [1572864,  1835008)  -> wcat+4194304
// wv:     [1835008,  2097152)  -> wcat+5242880
// wo:     [2097152,  3145728)  -> wob
// kc:     [3145728,  3538944)  -> kfull (row remap 1536->2048)
__global__ __launch_bounds__(256) void prep(const float* __restrict__ x,
                                            const float* __restrict__ wq,
                                            const float* __restrict__ wk,
                                            const float* __restrict__ wv,
                                            const float* __restrict__ wo,
                                            const float* __restrict__ kc,
                                            u16* __restrict__ xb,
                                            u16* __restrict__ wcat,
                                            u16* __restrict__ wob,
                                            u16* __restrict__ kfull) {
  const int c = blockIdx.x * 256 + threadIdx.x;
  const float* src;
  u16* dst;
  if (c < 524288) {
    src = x + (size_t)c * 4; dst = xb + (size_t)c * 4;
  } else if (c < 1572864) {
    size_t l = c - 524288; src = wq + l * 4; dst = wcat + l * 4;
  } else if (c < 1835008) {
    size_t l = c - 1572864; src = wk + l * 4; dst = wcat + 4194304 + l * 4;
  } else if (c < 2097152) {
    size_t l = c - 1835008; src = wv + l * 4; dst = wcat + 5242880 + l * 4;
  } else if (c < 3145728) {
    size_t l = c - 2097152; src = wo + l * 4; dst = wob + l * 4;
  } else {
    int l = c - 3145728;
    int bh = l / 24576, r = l - bh * 24576;
    src = kc + (size_t)bh * 98304 + (size_t)r * 4;
    dst = kfull + (size_t)bh * 131072 + (size_t)r * 4;
  }
  const float4 v = *(const float4*)src;
  ushort4 o;
  o.x = f2b(v.x); o.y = f2b(v.y); o.z = f2b(v.z); o.w = f2b(v.w);
  *(ushort4*)dst = o;
}

// v_cache [16][1536][64] f32 -> vT [16][64][2048] bf16 (cols 0..1535), LDS-tiled transpose
__global__ __launch_bounds__(256) void vcache_transpose(const float* __restrict__ vc,
                                                        u16* __restrict__ vT) {
  __shared__ float tile[64][65];
  const int bh = blockIdx.y, kt = blockIdx.x;
  const float* src = vc + ((size_t)bh * 1536 + (size_t)kt * 64) * 64;
  const int t = threadIdx.x;
#pragma unroll
  for (int j = 0; j < 4; j++) {
    int e = t + j * 256;            // 0..1023 chunks of 4
    int r = e >> 4, c = (e & 15) * 4;
    float4 v = *(const float4*)(src + (size_t)r * 64 + c);
    tile[r][c] = v.x; tile[r][c + 1] = v.y; tile[r][c + 2] = v.z; tile[r][c + 3] = v.w;
  }
  __syncthreads();
  int d = t >> 2, kv0 = (t & 3) * 16;
  u16* dst = vT + ((size_t)bh * 64 + d) * 2048 + (size_t)kt * 64 + kv0;
#pragma unroll
  for (int i = 0; i < 16; i++) dst[i] = f2b(tile[kv0 + i][d]);
}

// ---------------- GEMM: C[M][N] = A[M][K] * B[N][K]^T  (bf16 in, f32 out) ----------------
// 128x128 tile, BK=64, double-buffered LDS, 1 barrier/iter, XOR-swizzled granules.
__global__ __launch_bounds__(256, 2) void gemm_bt(const u16* __restrict__ A,
                                                  const u16* __restrict__ B,
                                                  float* __restrict__ C,
                                                  int M, int N, int K) {
  __shared__ __attribute__((aligned(16))) u16 As[2][8192];  // [buf][128 rows][64]
  __shared__ __attribute__((aligned(16))) u16 Bs[2][8192];
  const int t = threadIdx.x;
  const int lane = t & 63, w = t >> 6;
  const int wr = (w >> 1) * 64, wc = (w & 1) * 64;
  const int g = lane >> 4, cc = lane & 15;
  const size_t row0 = (size_t)blockIdx.x * 128, col0 = (size_t)blockIdx.y * 128;

  // staging geometry: 16B granules; lr = row-in-8, lc = granule col; swizzled source col
  const int lr = lane >> 3, lc = lane & 7;
  const int swz = lc ^ lr;
  const u16* aS = A + (row0 + w * 32 + lr) * (size_t)K + swz * 8;
  const u16* bS = B + (col0 + w * 32 + lr) * (size_t)K + swz * 8;

  f32x4 acc[4][4] = {};

#define GSTAGE(bufi, kk0)                                                      \
  {                                                                            \
    _Pragma("unroll") for (int i = 0; i < 4; i++) {                            \
      GLL(aS + (size_t)(i * 8) * K + (kk0), &As[bufi][(w * 32 + i * 8) * 64]); \
      GLL(bS + (size_t)(i * 8) * K + (kk0), &Bs[bufi][(w * 32 + i * 8) * 64]); \
    }                                                                          \
  }

  GSTAGE(0, 0);
  __syncthreads();

  const int niter = K >> 6;
  for (int it = 0; it < niter; ++it) {
    const int buf = it & 1;
    if (it + 1 < niter) GSTAGE(buf ^ 1, (it + 1) * 64);
    bf16x8 av[4][2], bv[4][2];
#pragma unroll
    for (int m = 0; m < 4; m++) {
      const int row = wr + m * 16 + cc;
#pragma unroll
      for (int kk = 0; kk < 2; kk++)
        av[m][kk] = *(const bf16x8*)(&As[buf][row * 64 + (((kk * 4 + g) ^ (cc & 7)) * 8)]);
    }
#pragma unroll
    for (int n = 0; n < 4; n++) {
      const int row = wc + n * 16 + cc;
#pragma unroll
      for (int kk = 0; kk < 2; kk++)
        bv[n][kk] = *(const bf16x8*)(&Bs[buf][row * 64 + (((kk * 4 + g) ^ (cc & 7)) * 8)]);
    }
#pragma unroll
    for (int kk = 0; kk < 2; kk++)
#pragma unroll
      for (int m = 0; m < 4; m++)
#pragma unroll
        for (int n = 0; n < 4; n++)
          acc[m][n] = MFMA16(av[m][kk], bv[n][kk], acc[m][n]);
    __syncthreads();
  }
#undef GSTAGE
#pragma unroll
  for (int m = 0; m < 4; m++)
#pragma unroll
    for (int n = 0; n < 4; n++)
#pragma unroll
      for (int r = 0; r < 4; r++)
        C[(row0 + wr + m * 16 + g * 4 + r) * N + (col0 + wc + n * 16 + cc)] = acc[m][n][r];
}

// ---------------- RoPE + scatter ----------------
// Cqkv [1024][3072] f32. q cols 0..2047, k cols 2048..2559, v cols 2560..3071
__global__ __launch_bounds__(256) void postproc(const float* __restrict__ Cqkv,
                                                const float* __restrict__ fcos,
                                                const float* __restrict__ fsin,
                                                u16* __restrict__ qrope,
                                                u16* __restrict__ kfull,
                                                u16* __restrict__ vT,
                                                float* __restrict__ newk,
                                                float* __restrict__ newv) {
  int idx = blockIdx.x * 256 + threadIdx.x;
  if (idx >= 1024 * 1536) return;
  int m = idx / 1536, p = idx - m * 1536;
  int b = m >> 9, s = m & 511;
  const float* row = Cqkv + (size_t)m * 3072;
  if (p < 1280) {
    bool isq = p < 1024;
    int pk = isq ? p : p - 1024;
    int h = pk >> 5, i = pk & 31;
    int colbase = (isq ? 0 : 2048) + h * 64 + 2 * i;
    float xr = row[colbase], xi = row[colbase + 1];
    float co = fcos[s * 32 + i], si = fsin[s * 32 + i];
    float orr = xr * co - xi * si;
    float oii = xr * si + xi * co;
    if (isq) {
      u16* dst = qrope + (((size_t)(b * 32 + h) * 512 + s) * 64 + 2 * i);
      dst[0] = f2b(orr); dst[1] = f2b(oii);
    } else {
      size_t o0 = ((size_t)(b * 8 + h) * 512 + s) * 64 + 2 * i;
      newk[o0] = orr; newk[o0 + 1] = oii;
      u16* kf = kfull + (((size_t)(b * 8 + h) * 2048 + 1536 + s) * 64 + 2 * i);
      kf[0] = f2b(orr); kf[1] = f2b(oii);
    }
  } else {
    int pv = p - 1280;
    int h = pv >> 5, i = pv & 31;
    float v0 = row[2560 + h * 64 + 2 * i], v1 = row[2560 + h * 64 + 2 * i + 1];
    size_t o0 = ((size_t)(b * 8 + h) * 512 + s) * 64 + 2 * i;
    newv[o0] = v0; newv[o0 + 1] = v1;
    u16* vt = vT + ((size_t)(b * 8 + h) * 64 + 2 * i) * 2048 + 1536 + s;
    vt[0] = f2b(v0); vt[2048] = f2b(v1);
  }
}

// ---------------- flash attention, KV-split 2-way, LDS-staged K/V ----------------
__global__ __launch_bounds__(256, 4) void attn_split(const u16* __restrict__ qrope,
                                                     const u16* __restrict__ kfull,
                                                     const u16* __restrict__ vT,
                                                     const float* __restrict__ mask,
                                                     float* __restrict__ po,
                                                     float* __restrict__ ml) {
  __shared__ __attribute__((aligned(16))) u16 Ks[2][4096];  // [buf][64 kv][64 d]
  __shared__ __attribute__((aligned(16))) u16 Vs[2][4096];  // [buf][64 d][64 kv]
  __shared__ __attribute__((aligned(16))) u16 P_lds[4096];  // 4 waves x 16x64
  const int t = threadIdx.x, lane = t & 63, w = t >> 6;
  const int g = lane >> 4, cc = lane & 15;
  // XCD-bijective swizzle: 1024 blocks -> 8 chunks of 128 (8 bh per XCD)
  const int p = blockIdx.x;
  const int v = (p & 7) * 128 + (p >> 3);
  const int bh = v >> 4, qt = (v >> 1) & 7, sp = v & 1;
  const int b = bh >> 5, h = bh & 31;
  const int bhkv = b * 8 + (h >> 2);
  const int s0 = qt * 64 + w * 16;
  const int j0beg = sp * 1024;

  const int lr = lane >> 3, lc = lane & 7;
  const int swzc = lc ^ lr;  // pre-swizzled source granule column

  bf16x8 qa0, qa1;
  {
    const u16* qb = qrope + ((size_t)bh * 512 + s0 + cc) * 64 + g * 8;
    qa0 = *(const bf16x8*)qb;
    qa1 = *(const bf16x8*)(qb + 32);
  }
  float mrow[4], ssum[4];
  f32x4 o[4] = {};
#pragma unroll
  for (int r = 0; r < 4; r++) { mrow[r] = -1e30f; ssum[r] = 0.0f; }

  u16* Pw = P_lds + w * 1024;
  const float* mbase = mask + (size_t)(s0 + g * 4) * 2048 + cc;
  const u16* ksrc0 = kfull + (size_t)bhkv * 131072 + (size_t)(w * 16 + lr) * 64 + swzc * 8;
  const u16* vsrc0 = vT + ((size_t)bhkv * 64 + w * 16 + lr) * 2048 + swzc * 8;

  {
    const u16* ks = ksrc0 + (size_t)j0beg * 64;
    const u16* vs = vsrc0 + j0beg;
    GLL(ks, &Ks[0][w * 1024]);
    GLL(ks + 8 * 64, &Ks[0][w * 1024 + 512]);
    GLL(vs, &Vs[0][w * 1024]);
    GLL(vs + 8 * 2048, &Vs[0][w * 1024 + 512]);
  }
  __syncthreads();

  for (int it = 0; it < 16; ++it) {
    const int buf = it & 1;
    const int j0 = j0beg + it * 64;
    if (it < 15) {  // stage next tile into buf^1 (overlaps with compute below)
      const u16* ks = ksrc0 + (size_t)(j0 + 64) * 64;
      const u16* vs = vsrc0 + (j0 + 64);
      GLL(ks, &Ks[buf ^ 1][w * 1024]);
      GLL(ks + 8 * 64, &Ks[buf ^ 1][w * 1024 + 512]);
      GLL(vs, &Vs[buf ^ 1][w * 1024]);
      GLL(vs + 8 * 2048, &Vs[buf ^ 1][w * 1024 + 512]);
    }

    // QK^T from LDS (swizzled reads)
    f32x4 sc[4];
#pragma unroll
    for (int jb = 0; jb < 4; jb++) {
      const bf16x8 k0 = *(const bf16x8*)(&Ks[buf][(jb * 16 + cc) * 64 + ((g ^ (cc & 7)) * 8)]);
      const bf16x8 k1 =
          *(const bf16x8*)(&Ks[buf][(jb * 16 + cc) * 64 + (((g + 4) ^ (cc & 7)) * 8)]);
      f32x4 z = {0.f, 0.f, 0.f, 0.f};
      z = MFMA16(qa0, k0, z);
      z = MFMA16(qa1, k1, z);
      sc[jb] = z;
    }
    // online softmax with defer-max (T13, THR=8)
    float pp[4][4];
#pragma unroll
    for (int r = 0; r < 4; r++) {
#pragma unroll
      for (int jb = 0; jb < 4; jb++)
        pp[r][jb] = sc[jb][r] * 0.125f + mbase[(size_t)r * 2048 + j0 + jb * 16];
      float tm = fmaxf(fmaxf(pp[r][0], pp[r][1]), fmaxf(pp[r][2], pp[r][3]));
#pragma unroll
      for (int off = 1; off < 16; off <<= 1) tm = fmaxf(tm, __shfl_xor(tm, off, 64));
      if (tm > mrow[r] + 8.0f) {  // rescale only on significant max growth
        float corr = __expf(mrow[r] - tm);
        mrow[r] = tm;
        ssum[r] *= corr;
#pragma unroll
        for (int db = 0; db < 4; db++) o[db][r] *= corr;
      }
      float ps = 0.f;
#pragma unroll
      for (int jb = 0; jb < 4; jb++) { pp[r][jb] = __expf(pp[r][jb] - mrow[r]); ps += pp[r][jb]; }
#pragma unroll
      for (int off = 1; off < 16; off <<= 1) ps += __shfl_xor(ps, off, 64);
      ssum[r] += ps;
      const int rowb = (g * 4 + r) * 128;
      const int sw = ((g * 4 + r) & 7) << 4;
#pragma unroll
      for (int jb = 0; jb < 4; jb++)
        Pw[((rowb + (jb * 16 + cc) * 2) ^ sw) >> 1] = f2b(pp[r][jb]);
    }
    // PV from LDS V (swizzled reads)
#pragma unroll
    for (int kk = 0; kk < 2; kk++) {
      const bf16x8 pa =
          *(const bf16x8*)(Pw + (((cc * 128 + kk * 64 + g * 16) ^ ((cc & 7) << 4)) >> 1));
#pragma unroll
      for (int db = 0; db < 4; db++) {
        const bf16x8 vf =
            *(const bf16x8*)(&Vs[buf][(db * 16 + cc) * 64 + (((kk * 4 + g) ^ (cc & 7)) * 8)]);
        o[db] = MFMA16(pa, vf, o[db]);
      }
    }
    __syncthreads();  // drains staging loads + protects buf reuse
  }
#pragma unroll
  for (int r = 0; r < 4; r++) {
    const size_t row = (size_t)bh * 512 + s0 + g * 4 + r;
    float* dst = po + (row * 2 + sp) * 64 + cc;
#pragma unroll
    for (int db = 0; db < 4; db++) dst[db * 16] = o[db][r];
    if (cc == 0) {
      float2* mlp = (float2*)ml;
      mlp[row * 2 + sp] = make_float2(mrow[r], ssum[r]);
    }
  }
}

// combine 2 splits -> aout bf16 [1024][2048] (b,s, h*64+d)
__global__ __launch_bounds__(256) void attn_combine(const float* __restrict__ po,
                                                    const float* __restrict__ ml,
                                                    u16* __restrict__ aout) {
  const int t = threadIdx.x;
  const int row = blockIdx.x * 4 + (t >> 6);  // bh*512 + s
  const int d = t & 63;
  const int bh = row >> 9, s = row & 511;
  const int b = bh >> 5, h = bh & 31;
  const float2* mlp = (const float2*)ml;
  const float2 m0 = mlp[row * 2 + 0], m1 = mlp[row * 2 + 1];
  const float M = fmaxf(m0.x, m1.x);
  const float w0 = __expf(m0.x - M), w1 = __expf(m1.x - M);
  const float L = m0.y * w0 + m1.y * w1;
  const float o = po[(size_t)(row * 2 + 0) * 64 + d] * w0 +
                  po[(size_t)(row * 2 + 1) * 64 + d] * w1;
  aout[((size_t)(b * 512 + s)) * 2048 + h * 64 + d] = f2b(o / L);
}

// ---------------- launch ----------------
extern "C" void kernel_launch(void* const* d_in, const int* in_sizes, int n_in,
                              void* d_out, int out_size, void* d_ws, size_t ws_size,
                              hipStream_t stream) {
  (void)in_sizes; (void)n_in; (void)out_size; (void)ws_size;
  const float* x    = (const float*)d_in[0];
  const float* fcos = (const float*)d_in[1];
  const float* fsin = (const float*)d_in[2];
  const float* kc   = (const float*)d_in[3];
  const float* vc   = (const float*)d_in[4];
  const float* mask = (const float*)d_in[5];
  const float* wq   = (const float*)d_in[6];
  const float* wk   = (const float*)d_in[7];
  const float* wv   = (const float*)d_in[8];
  const float* wo   = (const float*)d_in[9];

  float* out_f = (float*)d_out;                 // [2][512][2048]
  float* newk  = out_f + 2097152;               // [2][8][512][64]
  float* newv  = out_f + 2621440;               // [2][8][512][64]

  u16*   xb    = (u16*)d_ws;                    // 4MB   (dead after gemm1)
  u16*   wcat  = xb + 2097152;                  // 12MB  (dead after gemm1)
  u16*   wob   = wcat + 6291456;                // 8MB   (live until gemm2)
  float* Cqkv  = (float*)(wob + 4194304);       // 12MB  (dead after postproc)
  u16*   qrope = (u16*)(Cqkv + 3145728);        // 4MB
  u16*   kfull = qrope + 2097152;               // 4MB
  u16*   vTf   = kfull + 2097152;               // 4MB
  u16*   aout  = vTf + 2097152;                 // 4MB
  // aliases (live only during attention phase):
  float* po    = (float*)d_ws;                  // 16MB over xb+wcat
  float* ml    = Cqkv;                          // 0.5MB over Cqkv (dead after postproc)

  prep<<<13824, 256, 0, stream>>>(x, wq, wk, wv, wo, kc, xb, wcat, wob, kfull);
  vcache_transpose<<<dim3(24, 16), 256, 0, stream>>>(vc, vTf);

  gemm_bt<<<dim3(8, 24), 256, 0, stream>>>(xb, wcat, Cqkv, 1024, 3072, 2048);
  postproc<<<6144, 256, 0, stream>>>(Cqkv, fcos, fsin, qrope, kfull, vTf, newk, newv);
  attn_split<<<1024, 256, 0, stream>>>(qrope, kfull, vTf, mask, po, ml);
  attn_combine<<<8192, 256, 0, stream>>>(po, ml, aout);
  gemm_bt<<<dim3(8, 16), 256, 0, stream>>>(aout, wob, out_f, 1024, 2048, 2048);
}

// Round 8
// 152.542 us; speedup vs baseline: 1.8214x; 1.0976x over previous
//
#include <hip/hip_runtime.h>

typedef __attribute__((ext_vector_type(8))) short bf16x8;
typedef __attribute__((ext_vector_type(4))) float f32x4;
typedef unsigned short u16;

#define MFMA16(a, b, c) __builtin_amdgcn_mfma_f32_16x16x32_bf16(a, b, c, 0, 0, 0)
#define GLL(srcp, dstp) __builtin_amdgcn_global_load_lds(                      \
    (const __attribute__((address_space(1))) void*)(srcp),                     \
    (__attribute__((address_space(3))) void*)(dstp), 16, 0, 0)

__device__ __forceinline__ u16 f2b(float f) {
  union { float f; unsigned u; } a; a.f = f;
  return (u16)((a.u + 0x7FFFu + ((a.u >> 16) & 1u)) >> 16);
}

// ---------------- fused prep: f32->bf16 converts + k_cache copy ----------------
__global__ __launch_bounds__(256) void prep(const float* __restrict__ x,
                                            const float* __restrict__ wq,
                                            const float* __restrict__ wk,
                                            const float* __restrict__ wv,
                                            const float* __restrict__ wo,
                                            const float* __restrict__ kc,
                                            u16* __restrict__ xb,
                                            u16* __restrict__ wcat,
                                            u16* __restrict__ wob,
                                            u16* __restrict__ kfull) {
  const int c = blockIdx.x * 256 + threadIdx.x;
  const float* src;
  u16* dst;
  if (c < 524288) {
    src = x + (size_t)c * 4; dst = xb + (size_t)c * 4;
  } else if (c < 1572864) {
    size_t l = c - 524288; src = wq + l * 4; dst = wcat + l * 4;
  } else if (c < 1835008) {
    size_t l = c - 1572864; src = wk + l * 4; dst = wcat + 4194304 + l * 4;
  } else if (c < 2097152) {
    size_t l = c - 1835008; src = wv + l * 4; dst = wcat + 5242880 + l * 4;
  } else if (c < 3145728) {
    size_t l = c - 2097152; src = wo + l * 4; dst = wob + l * 4;
  } else {
    int l = c - 3145728;
    int bh = l / 24576, r = l - bh * 24576;
    src = kc + (size_t)bh * 98304 + (size_t)r * 4;
    dst = kfull + (size_t)bh * 131072 + (size_t)r * 4;
  }
  const float4 v = *(const float4*)src;
  ushort4 o;
  o.x = f2b(v.x); o.y = f2b(v.y); o.z = f2b(v.z); o.w = f2b(v.w);
  *(ushort4*)dst = o;
}

// v_cache [16][1536][64] f32 -> vT [16][64][2048] bf16 (cols 0..1535), LDS-tiled transpose
__global__ __launch_bounds__(256) void vcache_transpose(const float* __restrict__ vc,
                                                        u16* __restrict__ vT) {
  __shared__ float tile[64][65];
  const int bh = blockIdx.y, kt = blockIdx.x;
  const float* src = vc + ((size_t)bh * 1536 + (size_t)kt * 64) * 64;
  const int t = threadIdx.x;
#pragma unroll
  for (int j = 0; j < 4; j++) {
    int e = t + j * 256;            // 0..1023 chunks of 4
    int r = e >> 4, c = (e & 15) * 4;
    float4 v = *(const float4*)(src + (size_t)r * 64 + c);
    tile[r][c] = v.x; tile[r][c + 1] = v.y; tile[r][c + 2] = v.z; tile[r][c + 3] = v.w;
  }
  __syncthreads();
  int d = t >> 2, kv0 = (t & 3) * 16;
  u16* dst = vT + ((size_t)bh * 64 + d) * 2048 + (size_t)kt * 64 + kv0;
#pragma unroll
  for (int i = 0; i < 16; i++) dst[i] = f2b(tile[kv0 + i][d]);
}

// ---------------- GEMM: C[M][N] = A[M][K] * B[N][K]^T  (bf16 in, f32 out) ----------------
// 128x128 tile, BK=64, double-buffered LDS, 1 barrier/iter, XOR-swizzled granules.
__global__ __launch_bounds__(256, 2) void gemm_bt(const u16* __restrict__ A,
                                                  const u16* __restrict__ B,
                                                  float* __restrict__ C,
                                                  int M, int N, int K) {
  __shared__ __attribute__((aligned(16))) u16 As[2][8192];  // [buf][128 rows][64]
  __shared__ __attribute__((aligned(16))) u16 Bs[2][8192];
  const int t = threadIdx.x;
  const int lane = t & 63, w = t >> 6;
  const int wr = (w >> 1) * 64, wc = (w & 1) * 64;
  const int g = lane >> 4, cc = lane & 15;
  const size_t row0 = (size_t)blockIdx.x * 128, col0 = (size_t)blockIdx.y * 128;

  const int lr = lane >> 3, lc = lane & 7;
  const int swz = lc ^ lr;
  const u16* aS = A + (row0 + w * 32 + lr) * (size_t)K + swz * 8;
  const u16* bS = B + (col0 + w * 32 + lr) * (size_t)K + swz * 8;

  f32x4 acc[4][4] = {};

#define GSTAGE(bufi, kk0)                                                      \
  {                                                                            \
    _Pragma("unroll") for (int i = 0; i < 4; i++) {                            \
      GLL(aS + (size_t)(i * 8) * K + (kk0), &As[bufi][(w * 32 + i * 8) * 64]); \
      GLL(bS + (size_t)(i * 8) * K + (kk0), &Bs[bufi][(w * 32 + i * 8) * 64]); \
    }                                                                          \
  }

  GSTAGE(0, 0);
  __syncthreads();

  const int niter = K >> 6;
  for (int it = 0; it < niter; ++it) {
    const int buf = it & 1;
    if (it + 1 < niter) GSTAGE(buf ^ 1, (it + 1) * 64);
    bf16x8 av[4][2], bv[4][2];
#pragma unroll
    for (int m = 0; m < 4; m++) {
      const int row = wr + m * 16 + cc;
#pragma unroll
      for (int kk = 0; kk < 2; kk++)
        av[m][kk] = *(const bf16x8*)(&As[buf][row * 64 + (((kk * 4 + g) ^ (cc & 7)) * 8)]);
    }
#pragma unroll
    for (int n = 0; n < 4; n++) {
      const int row = wc + n * 16 + cc;
#pragma unroll
      for (int kk = 0; kk < 2; kk++)
        bv[n][kk] = *(const bf16x8*)(&Bs[buf][row * 64 + (((kk * 4 + g) ^ (cc & 7)) * 8)]);
    }
#pragma unroll
    for (int kk = 0; kk < 2; kk++)
#pragma unroll
      for (int m = 0; m < 4; m++)
#pragma unroll
        for (int n = 0; n < 4; n++)
          acc[m][n] = MFMA16(av[m][kk], bv[n][kk], acc[m][n]);
    __syncthreads();
  }
#undef GSTAGE
#pragma unroll
  for (int m = 0; m < 4; m++)
#pragma unroll
    for (int n = 0; n < 4; n++)
#pragma unroll
      for (int r = 0; r < 4; r++)
        C[(row0 + wr + m * 16 + g * 4 + r) * N + (col0 + wc + n * 16 + cc)] = acc[m][n][r];
}

// ---------------- RoPE + scatter ----------------
__global__ __launch_bounds__(256) void postproc(const float* __restrict__ Cqkv,
                                                const float* __restrict__ fcos,
                                                const float* __restrict__ fsin,
                                                u16* __restrict__ qrope,
                                                u16* __restrict__ kfull,
                                                u16* __restrict__ vT,
                                                float* __restrict__ newk,
                                                float* __restrict__ newv) {
  int idx = blockIdx.x * 256 + threadIdx.x;
  if (idx >= 1024 * 1536) return;
  int m = idx / 1536, p = idx - m * 1536;
  int b = m >> 9, s = m & 511;
  const float* row = Cqkv + (size_t)m * 3072;
  if (p < 1280) {
    bool isq = p < 1024;
    int pk = isq ? p : p - 1024;
    int h = pk >> 5, i = pk & 31;
    int colbase = (isq ? 0 : 2048) + h * 64 + 2 * i;
    float xr = row[colbase], xi = row[colbase + 1];
    float co = fcos[s * 32 + i], si = fsin[s * 32 + i];
    float orr = xr * co - xi * si;
    float oii = xr * si + xi * co;
    if (isq) {
      u16* dst = qrope + (((size_t)(b * 32 + h) * 512 + s) * 64 + 2 * i);
      dst[0] = f2b(orr); dst[1] = f2b(oii);
    } else {
      size_t o0 = ((size_t)(b * 8 + h) * 512 + s) * 64 + 2 * i;
      newk[o0] = orr; newk[o0 + 1] = oii;
      u16* kf = kfull + (((size_t)(b * 8 + h) * 2048 + 1536 + s) * 64 + 2 * i);
      kf[0] = f2b(orr); kf[1] = f2b(oii);
    }
  } else {
    int pv = p - 1280;
    int h = pv >> 5, i = pv & 31;
    float v0 = row[2560 + h * 64 + 2 * i], v1 = row[2560 + h * 64 + 2 * i + 1];
    size_t o0 = ((size_t)(b * 8 + h) * 512 + s) * 64 + 2 * i;
    newv[o0] = v0; newv[o0 + 1] = v1;
    u16* vt = vT + ((size_t)(b * 8 + h) * 64 + 2 * i) * 2048 + 1536 + s;
    vt[0] = f2b(v0); vt[2048] = f2b(v1);
  }
}

// ---------------- flash attention, KV-split 2-way, LDS-staged K/V ----------------
// Ballot-gated defer-max + per-lane deferred sum: common path has NO shuffle chains.
__global__ __launch_bounds__(256, 4) void attn_split(const u16* __restrict__ qrope,
                                                     const u16* __restrict__ kfull,
                                                     const u16* __restrict__ vT,
                                                     const float* __restrict__ mask,
                                                     float* __restrict__ po,
                                                     float* __restrict__ ml) {
  __shared__ __attribute__((aligned(16))) u16 Ks[2][4096];  // [buf][64 kv][64 d]
  __shared__ __attribute__((aligned(16))) u16 Vs[2][4096];  // [buf][64 d][64 kv]
  __shared__ __attribute__((aligned(16))) u16 P_lds[4096];  // 4 waves x 16x64
  const int t = threadIdx.x, lane = t & 63, w = t >> 6;
  const int g = lane >> 4, cc = lane & 15;
  // XCD-bijective swizzle: 1024 blocks -> 8 chunks of 128 (8 bh per XCD)
  const int p = blockIdx.x;
  const int v = (p & 7) * 128 + (p >> 3);
  const int bh = v >> 4, qt = (v >> 1) & 7, sp = v & 1;
  const int b = bh >> 5, h = bh & 31;
  const int bhkv = b * 8 + (h >> 2);
  const int s0 = qt * 64 + w * 16;
  const int j0beg = sp * 1024;

  const int lr = lane >> 3, lc = lane & 7;
  const int swzc = lc ^ lr;  // pre-swizzled source granule column

  bf16x8 qa0, qa1;
  {
    const u16* qb = qrope + ((size_t)bh * 512 + s0 + cc) * 64 + g * 8;
    qa0 = *(const bf16x8*)qb;
    qa1 = *(const bf16x8*)(qb + 32);
  }
  float mrow[4], lsum[4];  // mrow uniform per 16-lane group; lsum per-lane partial
  f32x4 o[4] = {};
#pragma unroll
  for (int r = 0; r < 4; r++) { mrow[r] = -1e30f; lsum[r] = 0.0f; }

  u16* Pw = P_lds + w * 1024;
  const float* mbase = mask + (size_t)(s0 + g * 4) * 2048 + cc;
  const u16* ksrc0 = kfull + (size_t)bhkv * 131072 + (size_t)(w * 16 + lr) * 64 + swzc * 8;
  const u16* vsrc0 = vT + ((size_t)bhkv * 64 + w * 16 + lr) * 2048 + swzc * 8;

  {
    const u16* ks = ksrc0 + (size_t)j0beg * 64;
    const u16* vs = vsrc0 + j0beg;
    GLL(ks, &Ks[0][w * 1024]);
    GLL(ks + 8 * 64, &Ks[0][w * 1024 + 512]);
    GLL(vs, &Vs[0][w * 1024]);
    GLL(vs + 8 * 2048, &Vs[0][w * 1024 + 512]);
  }
  __syncthreads();

  for (int it = 0; it < 16; ++it) {
    const int buf = it & 1;
    const int j0 = j0beg + it * 64;
    if (it < 15) {  // stage next tile into buf^1 (overlaps with compute below)
      const u16* ks = ksrc0 + (size_t)(j0 + 64) * 64;
      const u16* vs = vsrc0 + (j0 + 64);
      GLL(ks, &Ks[buf ^ 1][w * 1024]);
      GLL(ks + 8 * 64, &Ks[buf ^ 1][w * 1024 + 512]);
      GLL(vs, &Vs[buf ^ 1][w * 1024]);
      GLL(vs + 8 * 2048, &Vs[buf ^ 1][w * 1024 + 512]);
    }

    // QK^T from LDS (swizzled reads)
    f32x4 sc[4];
#pragma unroll
    for (int jb = 0; jb < 4; jb++) {
      const bf16x8 k0 = *(const bf16x8*)(&Ks[buf][(jb * 16 + cc) * 64 + ((g ^ (cc & 7)) * 8)]);
      const bf16x8 k1 =
          *(const bf16x8*)(&Ks[buf][(jb * 16 + cc) * 64 + (((g + 4) ^ (cc & 7)) * 8)]);
      f32x4 z = {0.f, 0.f, 0.f, 0.f};
      z = MFMA16(qa0, k0, z);
      z = MFMA16(qa1, k1, z);
      sc[jb] = z;
    }
    // softmax: ballot-gated defer-max, per-lane deferred sum
    float pp[4][4];
#pragma unroll
    for (int r = 0; r < 4; r++) {
#pragma unroll
      for (int jb = 0; jb < 4; jb++)
        pp[r][jb] = sc[jb][r] * 0.125f + mbase[(size_t)r * 2048 + j0 + jb * 16];
      const float lm = fmaxf(fmaxf(pp[r][0], pp[r][1]), fmaxf(pp[r][2], pp[r][3]));
      if (__any(lm > mrow[r] + 8.0f)) {  // rare after iter 0
        float tm = lm;
#pragma unroll
        for (int off = 1; off < 16; off <<= 1) tm = fmaxf(tm, __shfl_xor(tm, off, 64));
        const float newm = fmaxf(mrow[r], tm);
        const float corr = __expf(mrow[r] - newm);
        mrow[r] = newm;
        lsum[r] *= corr;
#pragma unroll
        for (int db = 0; db < 4; db++) o[db][r] *= corr;
      }
      float ps = 0.f;
#pragma unroll
      for (int jb = 0; jb < 4; jb++) { pp[r][jb] = __expf(pp[r][jb] - mrow[r]); ps += pp[r][jb]; }
      lsum[r] += ps;  // per-lane partial; cross-lane reduce after the loop
      const int rowb = (g * 4 + r) * 128;
      const int sw = ((g * 4 + r) & 7) << 4;
#pragma unroll
      for (int jb = 0; jb < 4; jb++)
        Pw[((rowb + (jb * 16 + cc) * 2) ^ sw) >> 1] = f2b(pp[r][jb]);
    }
    // PV from LDS V (swizzled reads)
#pragma unroll
    for (int kk = 0; kk < 2; kk++) {
      const bf16x8 pa =
          *(const bf16x8*)(Pw + (((cc * 128 + kk * 64 + g * 16) ^ ((cc & 7) << 4)) >> 1));
#pragma unroll
      for (int db = 0; db < 4; db++) {
        const bf16x8 vf =
            *(const bf16x8*)(&Vs[buf][(db * 16 + cc) * 64 + (((kk * 4 + g) ^ (cc & 7)) * 8)]);
        o[db] = MFMA16(pa, vf, o[db]);
      }
    }
    __syncthreads();  // drains staging loads + protects buf reuse
  }
#pragma unroll
  for (int r = 0; r < 4; r++) {
    float ps = lsum[r];
#pragma unroll
    for (int off = 1; off < 16; off <<= 1) ps += __shfl_xor(ps, off, 64);
    const size_t row = (size_t)bh * 512 + s0 + g * 4 + r;
    float* dst = po + (row * 2 + sp) * 64 + cc;
#pragma unroll
    for (int db = 0; db < 4; db++) dst[db * 16] = o[db][r];
    if (cc == 0) {
      float2* mlp = (float2*)ml;
      mlp[row * 2 + sp] = make_float2(mrow[r], ps);
    }
  }
}

// combine 2 splits -> aout bf16 [1024][2048] (b,s, h*64+d)
__global__ __launch_bounds__(256) void attn_combine(const float* __restrict__ po,
                                                    const float* __restrict__ ml,
                                                    u16* __restrict__ aout) {
  const int t = threadIdx.x;
  const int row = blockIdx.x * 4 + (t >> 6);  // bh*512 + s
  const int d = t & 63;
  const int bh = row >> 9, s = row & 511;
  const int b = bh >> 5, h = bh & 31;
  const float2* mlp = (const float2*)ml;
  const float2 m0 = mlp[row * 2 + 0], m1 = mlp[row * 2 + 1];
  const float M = fmaxf(m0.x, m1.x);
  const float w0 = __expf(m0.x - M), w1 = __expf(m1.x - M);
  const float L = m0.y * w0 + m1.y * w1;
  const float o = po[(size_t)(row * 2 + 0) * 64 + d] * w0 +
                  po[(size_t)(row * 2 + 1) * 64 + d] * w1;
  aout[((size_t)(b * 512 + s)) * 2048 + h * 64 + d] = f2b(o / L);
}

// ---------------- launch ----------------
extern "C" void kernel_launch(void* const* d_in, const int* in_sizes, int n_in,
                              void* d_out, int out_size, void* d_ws, size_t ws_size,
                              hipStream_t stream) {
  (void)in_sizes; (void)n_in; (void)out_size; (void)ws_size;
  const float* x    = (const float*)d_in[0];
  const float* fcos = (const float*)d_in[1];
  const float* fsin = (const float*)d_in[2];
  const float* kc   = (const float*)d_in[3];
  const float* vc   = (const float*)d_in[4];
  const float* mask = (const float*)d_in[5];
  const float* wq   = (const float*)d_in[6];
  const float* wk   = (const float*)d_in[7];
  const float* wv   = (const float*)d_in[8];
  const float* wo   = (const float*)d_in[9];

  float* out_f = (float*)d_out;                 // [2][512][2048]
  float* newk  = out_f + 2097152;               // [2][8][512][64]
  float* newv  = out_f + 2621440;               // [2][8][512][64]

  u16*   xb    = (u16*)d_ws;                    // 4MB   (dead after gemm1)
  u16*   wcat  = xb + 2097152;                  // 12MB  (dead after gemm1)
  u16*   wob   = wcat + 6291456;                // 8MB   (live until gemm2)
  float* Cqkv  = (float*)(wob + 4194304);       // 12MB  (dead after postproc)
  u16*   qrope = (u16*)(Cqkv + 3145728);        // 4MB
  u16*   kfull = qrope + 2097152;               // 4MB
  u16*   vTf   = kfull + 2097152;               // 4MB
  u16*   aout  = vTf + 2097152;                 // 4MB
  // aliases (live only during attention phase):
  float* po    = (float*)d_ws;                  // 16MB over xb+wcat
  float* ml    = Cqkv;                          // 0.5MB over Cqkv (dead after postproc)

  prep<<<13824, 256, 0, stream>>>(x, wq, wk, wv, wo, kc, xb, wcat, wob, kfull);
  vcache_transpose<<<dim3(24, 16), 256, 0, stream>>>(vc, vTf);

  gemm_bt<<<dim3(8, 24), 256, 0, stream>>>(xb, wcat, Cqkv, 1024, 3072, 2048);
  postproc<<<6144, 256, 0, stream>>>(Cqkv, fcos, fsin, qrope, kfull, vTf, newk, newv);
  attn_split<<<1024, 256, 0, stream>>>(qrope, kfull, vTf, mask, po, ml);
  attn_combine<<<8192, 256, 0, stream>>>(po, ml, aout);
  gemm_bt<<<dim3(8, 16), 256, 0, stream>>>(aout, wob, out_f, 1024, 2048, 2048);
}

// Round 9
// 147.650 us; speedup vs baseline: 1.8818x; 1.0331x over previous
//
#include <hip/hip_runtime.h>

typedef __attribute__((ext_vector_type(8))) short bf16x8;
typedef __attribute__((ext_vector_type(4))) float f32x4;
typedef unsigned short u16;

#define MFMA16(a, b, c) __builtin_amdgcn_mfma_f32_16x16x32_bf16(a, b, c, 0, 0, 0)
#define GLL(srcp, dstp) __builtin_amdgcn_global_load_lds(                      \
    (const __attribute__((address_space(1))) void*)(srcp),                     \
    (__attribute__((address_space(3))) void*)(dstp), 16, 0, 0)

__device__ __forceinline__ u16 f2b(float f) {
  union { float f; unsigned u; } a; a.f = f;
  return (u16)((a.u + 0x7FFFu + ((a.u >> 16) & 1u)) >> 16);
}

// ---------------- fused prep: f32->bf16 converts + k_cache copy ----------------
__global__ __launch_bounds__(256) void prep(const float* __restrict__ x,
                                            const float* __restrict__ wq,
                                            const float* __restrict__ wk,
                                            const float* __restrict__ wv,
                                            const float* __restrict__ wo,
                                            const float* __restrict__ kc,
                                            u16* __restrict__ xb,
                                            u16* __restrict__ wcat,
                                            u16* __restrict__ wob,
                                            u16* __restrict__ kfull) {
  const int c = blockIdx.x * 256 + threadIdx.x;
  const float* src;
  u16* dst;
  if (c < 524288) {
    src = x + (size_t)c * 4; dst = xb + (size_t)c * 4;
  } else if (c < 1572864) {
    size_t l = c - 524288; src = wq + l * 4; dst = wcat + l * 4;
  } else if (c < 1835008) {
    size_t l = c - 1572864; src = wk + l * 4; dst = wcat + 4194304 + l * 4;
  } else if (c < 2097152) {
    size_t l = c - 1835008; src = wv + l * 4; dst = wcat + 5242880 + l * 4;
  } else if (c < 3145728) {
    size_t l = c - 2097152; src = wo + l * 4; dst = wob + l * 4;
  } else {
    int l = c - 3145728;
    int bh = l / 24576, r = l - bh * 24576;
    src = kc + (size_t)bh * 98304 + (size_t)r * 4;
    dst = kfull + (size_t)bh * 131072 + (size_t)r * 4;
  }
  const float4 v = *(const float4*)src;
  ushort4 o;
  o.x = f2b(v.x); o.y = f2b(v.y); o.z = f2b(v.z); o.w = f2b(v.w);
  *(ushort4*)dst = o;
}

// unified V transpose -> vT [16][64][2048] bf16
// kt<24: v_cache [16][1536][64] f32 (cols 0..1535); kt>=24: newv [16][512][64] f32 (cols 1536..2047)
__global__ __launch_bounds__(256) void vtr(const float* __restrict__ vc,
                                           const float* __restrict__ newv,
                                           u16* __restrict__ vT) {
  __shared__ float tile[64][65];
  const int kt = blockIdx.x, bh = blockIdx.y;
  const float* src;
  int colbase;
  if (kt < 24) {
    src = vc + ((size_t)bh * 1536 + (size_t)kt * 64) * 64;
    colbase = kt * 64;
  } else {
    src = newv + ((size_t)bh * 512 + (size_t)(kt - 24) * 64) * 64;
    colbase = 1536 + (kt - 24) * 64;
  }
  const int t = threadIdx.x;
#pragma unroll
  for (int j = 0; j < 4; j++) {
    int e = t + j * 256;            // 0..1023 chunks of 4
    int r = e >> 4, c = (e & 15) * 4;
    float4 v = *(const float4*)(src + (size_t)r * 64 + c);
    tile[r][c] = v.x; tile[r][c + 1] = v.y; tile[r][c + 2] = v.z; tile[r][c + 3] = v.w;
  }
  __syncthreads();
  int d = t >> 2, kv0 = (t & 3) * 16;
  u16* dst = vT + ((size_t)bh * 64 + d) * 2048 + colbase + kv0;
#pragma unroll
  for (int i = 0; i < 16; i++) dst[i] = f2b(tile[kv0 + i][d]);
}

// ---------------- GEMM: C[M][N] = A[M][K] * B[N][K]^T  (bf16 in, f32 out) ----------------
// 128x128 tile, BK=64, depth-3 pipeline (4 LDS buffers), counted vmcnt + raw barrier.
__global__ __launch_bounds__(256, 1) void gemm_bt(const u16* __restrict__ A,
                                                  const u16* __restrict__ B,
                                                  float* __restrict__ C,
                                                  int M, int N, int K) {
  __shared__ __attribute__((aligned(16))) u16 As[4][8192];  // 4 bufs x 128x64
  __shared__ __attribute__((aligned(16))) u16 Bs[4][8192];  // 128 KB total
  const int t = threadIdx.x;
  const int lane = t & 63, w = t >> 6;
  const int wr = (w >> 1) * 64, wc = (w & 1) * 64;
  const int g = lane >> 4, cc = lane & 15;
  const size_t row0 = (size_t)blockIdx.x * 128, col0 = (size_t)blockIdx.y * 128;

  const int lr = lane >> 3, lc = lane & 7;
  const int swz = lc ^ lr;
  const u16* aS = A + (row0 + w * 32 + lr) * (size_t)K + swz * 8;
  const u16* bS = B + (col0 + w * 32 + lr) * (size_t)K + swz * 8;

  f32x4 acc[4][4] = {};

#define GSTAGE(bufi, kk0)                                                      \
  {                                                                            \
    _Pragma("unroll") for (int i = 0; i < 4; i++) {                            \
      GLL(aS + (size_t)(i * 8) * K + (kk0), &As[bufi][(w * 32 + i * 8) * 64]); \
      GLL(bS + (size_t)(i * 8) * K + (kk0), &Bs[bufi][(w * 32 + i * 8) * 64]); \
    }                                                                          \
  }

  const int niter = K >> 6;  // >= 3 required (K=2048 -> 32)
  GSTAGE(0, 0);
  GSTAGE(1, 64);
  GSTAGE(2, 128);
  asm volatile("s_waitcnt vmcnt(16)" ::: "memory");
  __builtin_amdgcn_s_barrier();

  for (int it = 0; it < niter; ++it) {
    const int buf = it & 3;
    if (it + 3 < niter) GSTAGE((it + 3) & 3, (it + 3) * 64);
    bf16x8 av[4][2], bv[4][2];
#pragma unroll
    for (int m = 0; m < 4; m++) {
      const int row = wr + m * 16 + cc;
#pragma unroll
      for (int kk = 0; kk < 2; kk++)
        av[m][kk] = *(const bf16x8*)(&As[buf][row * 64 + (((kk * 4 + g) ^ (cc & 7)) * 8)]);
    }
#pragma unroll
    for (int n = 0; n < 4; n++) {
      const int row = wc + n * 16 + cc;
#pragma unroll
      for (int kk = 0; kk < 2; kk++)
        bv[n][kk] = *(const bf16x8*)(&Bs[buf][row * 64 + (((kk * 4 + g) ^ (cc & 7)) * 8)]);
    }
#pragma unroll
    for (int kk = 0; kk < 2; kk++)
#pragma unroll
      for (int m = 0; m < 4; m++)
#pragma unroll
        for (int n = 0; n < 4; n++)
          acc[m][n] = MFMA16(av[m][kk], bv[n][kk], acc[m][n]);
    // end-of-iter: wait only until the NEXT tile's stages are guaranteed done
    if (it + 4 <= niter) {
      asm volatile("s_waitcnt vmcnt(16)" ::: "memory");
    } else if (it + 3 == niter) {
      asm volatile("s_waitcnt vmcnt(8)" ::: "memory");
    } else if (it + 2 == niter) {
      asm volatile("s_waitcnt vmcnt(0)" ::: "memory");
    }
    if (it + 1 < niter) __builtin_amdgcn_s_barrier();
  }
#undef GSTAGE
#pragma unroll
  for (int m = 0; m < 4; m++)
#pragma unroll
    for (int n = 0; n < 4; n++)
#pragma unroll
      for (int r = 0; r < 4; r++)
        C[(row0 + wr + m * 16 + g * 4 + r) * N + (col0 + wc + n * 16 + cc)] = acc[m][n][r];
}

// ---------------- RoPE + scatter (no vT writes — vtr handles them) ----------------
__global__ __launch_bounds__(256) void postproc(const float* __restrict__ Cqkv,
                                                const float* __restrict__ fcos,
                                                const float* __restrict__ fsin,
                                                u16* __restrict__ qrope,
                                                u16* __restrict__ kfull,
                                                float* __restrict__ newk,
                                                float* __restrict__ newv) {
  int idx = blockIdx.x * 256 + threadIdx.x;
  if (idx >= 1024 * 1536) return;
  int m = idx / 1536, p = idx - m * 1536;
  int b = m >> 9, s = m & 511;
  const float* row = Cqkv + (size_t)m * 3072;
  if (p < 1280) {
    bool isq = p < 1024;
    int pk = isq ? p : p - 1024;
    int h = pk >> 5, i = pk & 31;
    int colbase = (isq ? 0 : 2048) + h * 64 + 2 * i;
    float xr = row[colbase], xi = row[colbase + 1];
    float co = fcos[s * 32 + i], si = fsin[s * 32 + i];
    float orr = xr * co - xi * si;
    float oii = xr * si + xi * co;
    if (isq) {
      u16* dst = qrope + (((size_t)(b * 32 + h) * 512 + s) * 64 + 2 * i);
      dst[0] = f2b(orr); dst[1] = f2b(oii);
    } else {
      size_t o0 = ((size_t)(b * 8 + h) * 512 + s) * 64 + 2 * i;
      newk[o0] = orr; newk[o0 + 1] = oii;
      u16* kf = kfull + (((size_t)(b * 8 + h) * 2048 + 1536 + s) * 64 + 2 * i);
      kf[0] = f2b(orr); kf[1] = f2b(oii);
    }
  } else {
    int pv = p - 1280;
    int h = pv >> 5, i = pv & 31;
    float v0 = row[2560 + h * 64 + 2 * i], v1 = row[2560 + h * 64 + 2 * i + 1];
    size_t o0 = ((size_t)(b * 8 + h) * 512 + s) * 64 + 2 * i;
    newv[o0] = v0; newv[o0 + 1] = v1;
  }
}

// ---------------- flash attention: 8-wave blocks, KV-split 2-way, LDS-staged K/V ----------------
// 512 blocks = 2/CU resident, no tail. Each wave owns 16 q-rows; block covers 128 q-rows.
__global__ __launch_bounds__(512, 4) void attn_split(const u16* __restrict__ qrope,
                                                     const u16* __restrict__ kfull,
                                                     const u16* __restrict__ vT,
                                                     const float* __restrict__ mask,
                                                     float* __restrict__ po,
                                                     float* __restrict__ ml) {
  __shared__ __attribute__((aligned(16))) u16 Ks[2][4096];  // [buf][64 kv][64 d]
  __shared__ __attribute__((aligned(16))) u16 Vs[2][4096];  // [buf][64 d][64 kv]
  __shared__ __attribute__((aligned(16))) u16 P_lds[8192];  // 8 waves x 16x64
  const int t = threadIdx.x, lane = t & 63, w = t >> 6;  // w in 0..7
  const int g = lane >> 4, cc = lane & 15;
  // XCD-bijective swizzle: 512 blocks -> 8 chunks of 64 (8 bh per XCD)
  const int p = blockIdx.x;
  const int v = (p & 7) * 64 + (p >> 3);
  const int bh = v >> 3, qt = (v >> 1) & 3, sp = v & 1;
  const int b = bh >> 5, h = bh & 31;
  const int bhkv = b * 8 + (h >> 2);
  const int s0 = qt * 128 + w * 16;
  const int j0beg = sp * 1024;

  const int lr = lane >> 3, lc = lane & 7;
  const int swzc = lc ^ lr;  // pre-swizzled source granule column

  bf16x8 qa0, qa1;
  {
    const u16* qb = qrope + ((size_t)bh * 512 + s0 + cc) * 64 + g * 8;
    qa0 = *(const bf16x8*)qb;
    qa1 = *(const bf16x8*)(qb + 32);
  }
  float mrow[4], lsum[4];
  f32x4 o[4] = {};
#pragma unroll
  for (int r = 0; r < 4; r++) { mrow[r] = -1e30f; lsum[r] = 0.0f; }

  u16* Pw = P_lds + w * 1024;
  const float* mbase = mask + (size_t)(s0 + g * 4) * 2048 + cc;
  // wave w stages rows w*8 + lr of each 64-row tile (1 GLL for K, 1 for V)
  const u16* ksrc0 = kfull + (size_t)bhkv * 131072 + (size_t)(w * 8 + lr) * 64 + swzc * 8;
  const u16* vsrc0 = vT + ((size_t)bhkv * 64 + w * 8 + lr) * 2048 + swzc * 8;

  GLL(ksrc0 + (size_t)j0beg * 64, &Ks[0][w * 512]);
  GLL(vsrc0 + j0beg, &Vs[0][w * 512]);
  __syncthreads();

  for (int it = 0; it < 16; ++it) {
    const int buf = it & 1;
    const int j0 = j0beg + it * 64;
    if (it < 15) {  // stage next tile (overlaps with compute)
      GLL(ksrc0 + (size_t)(j0 + 64) * 64, &Ks[buf ^ 1][w * 512]);
      GLL(vsrc0 + (j0 + 64), &Vs[buf ^ 1][w * 512]);
    }
    // hoist mask loads (independent of QK^T)
    float mk[4][4];
#pragma unroll
    for (int r = 0; r < 4; r++)
#pragma unroll
      for (int jb = 0; jb < 4; jb++)
        mk[r][jb] = mbase[(size_t)r * 2048 + j0 + jb * 16];

    // QK^T from LDS (swizzled reads)
    f32x4 sc[4];
#pragma unroll
    for (int jb = 0; jb < 4; jb++) {
      const bf16x8 k0 = *(const bf16x8*)(&Ks[buf][(jb * 16 + cc) * 64 + ((g ^ (cc & 7)) * 8)]);
      const bf16x8 k1 =
          *(const bf16x8*)(&Ks[buf][(jb * 16 + cc) * 64 + (((g + 4) ^ (cc & 7)) * 8)]);
      f32x4 z = {0.f, 0.f, 0.f, 0.f};
      z = MFMA16(qa0, k0, z);
      z = MFMA16(qa1, k1, z);
      sc[jb] = z;
    }
    // softmax: ballot-gated defer-max, per-lane deferred sum
    float pp[4][4];
#pragma unroll
    for (int r = 0; r < 4; r++) {
#pragma unroll
      for (int jb = 0; jb < 4; jb++)
        pp[r][jb] = sc[jb][r] * 0.125f + mk[r][jb];
      const float lm = fmaxf(fmaxf(pp[r][0], pp[r][1]), fmaxf(pp[r][2], pp[r][3]));
      if (__any(lm > mrow[r] + 8.0f)) {  // rare after iter 0
        float tm = lm;
#pragma unroll
        for (int off = 1; off < 16; off <<= 1) tm = fmaxf(tm, __shfl_xor(tm, off, 64));
        const float newm = fmaxf(mrow[r], tm);
        const float corr = __expf(mrow[r] - newm);
        mrow[r] = newm;
        lsum[r] *= corr;
#pragma unroll
        for (int db = 0; db < 4; db++) o[db][r] *= corr;
      }
      float ps = 0.f;
#pragma unroll
      for (int jb = 0; jb < 4; jb++) { pp[r][jb] = __expf(pp[r][jb] - mrow[r]); ps += pp[r][jb]; }
      lsum[r] += ps;
      const int rowb = (g * 4 + r) * 128;
      const int sw = ((g * 4 + r) & 7) << 4;
#pragma unroll
      for (int jb = 0; jb < 4; jb++)
        Pw[((rowb + (jb * 16 + cc) * 2) ^ sw) >> 1] = f2b(pp[r][jb]);
    }
    // PV from LDS V (swizzled reads)
#pragma unroll
    for (int kk = 0; kk < 2; kk++) {
      const bf16x8 pa =
          *(const bf16x8*)(Pw + (((cc * 128 + kk * 64 + g * 16) ^ ((cc & 7) << 4)) >> 1));
#pragma unroll
      for (int db = 0; db < 4; db++) {
        const bf16x8 vf =
            *(const bf16x8*)(&Vs[buf][(db * 16 + cc) * 64 + (((kk * 4 + g) ^ (cc & 7)) * 8)]);
        o[db] = MFMA16(pa, vf, o[db]);
      }
    }
    __syncthreads();  // drains staging loads + protects buf reuse
  }
#pragma unroll
  for (int r = 0; r < 4; r++) {
    float ps = lsum[r];
#pragma unroll
    for (int off = 1; off < 16; off <<= 1) ps += __shfl_xor(ps, off, 64);
    const size_t row = (size_t)bh * 512 + s0 + g * 4 + r;
    float* dst = po + (row * 2 + sp) * 64 + cc;
#pragma unroll
    for (int db = 0; db < 4; db++) dst[db * 16] = o[db][r];
    if (cc == 0) {
      float2* mlp = (float2*)ml;
      mlp[row * 2 + sp] = make_float2(mrow[r], ps);
    }
  }
}

// combine 2 splits -> aout bf16 [1024][2048] (b,s, h*64+d)
__global__ __launch_bounds__(256) void attn_combine(const float* __restrict__ po,
                                                    const float* __restrict__ ml,
                                                    u16* __restrict__ aout) {
  const int t = threadIdx.x;
  const int row = blockIdx.x * 4 + (t >> 6);  // bh*512 + s
  const int d = t & 63;
  const int bh = row >> 9, s = row & 511;
  const int b = bh >> 5, h = bh & 31;
  const float2* mlp = (const float2*)ml;
  const float2 m0 = mlp[row * 2 + 0], m1 = mlp[row * 2 + 1];
  const float M = fmaxf(m0.x, m1.x);
  const float w0 = __expf(m0.x - M), w1 = __expf(m1.x - M);
  const float L = m0.y * w0 + m1.y * w1;
  const float o = po[(size_t)(row * 2 + 0) * 64 + d] * w0 +
                  po[(size_t)(row * 2 + 1) * 64 + d] * w1;
  aout[((size_t)(b * 512 + s)) * 2048 + h * 64 + d] = f2b(o / L);
}

// ---------------- launch ----------------
extern "C" void kernel_launch(void* const* d_in, const int* in_sizes, int n_in,
                              void* d_out, int out_size, void* d_ws, size_t ws_size,
                              hipStream_t stream) {
  (void)in_sizes; (void)n_in; (void)out_size; (void)ws_size;
  const float* x    = (const float*)d_in[0];
  const float* fcos = (const float*)d_in[1];
  const float* fsin = (const float*)d_in[2];
  const float* kc   = (const float*)d_in[3];
  const float* vc   = (const float*)d_in[4];
  const float* mask = (const float*)d_in[5];
  const float* wq   = (const float*)d_in[6];
  const float* wk   = (const float*)d_in[7];
  const float* wv   = (const float*)d_in[8];
  const float* wo   = (const float*)d_in[9];

  float* out_f = (float*)d_out;                 // [2][512][2048]
  float* newk  = out_f + 2097152;               // [2][8][512][64]
  float* newv  = out_f + 2621440;               // [2][8][512][64]

  u16*   xb    = (u16*)d_ws;                    // 4MB   (dead after gemm1)
  u16*   wcat  = xb + 2097152;                  // 12MB  (dead after gemm1)
  u16*   wob   = wcat + 6291456;                // 8MB   (live until gemm2)
  float* Cqkv  = (float*)(wob + 4194304);       // 12MB  (dead after postproc)
  u16*   qrope = (u16*)(Cqkv + 3145728);        // 4MB
  u16*   kfull = qrope + 2097152;               // 4MB
  u16*   vTf   = kfull + 2097152;               // 4MB
  u16*   aout  = vTf + 2097152;                 // 4MB
  // aliases (live only during attention phase):
  float* po    = (float*)d_ws;                  // 16MB over xb+wcat
  float* ml    = Cqkv;                          // 0.5MB over Cqkv (dead after postproc)

  prep<<<13824, 256, 0, stream>>>(x, wq, wk, wv, wo, kc, xb, wcat, wob, kfull);

  gemm_bt<<<dim3(8, 24), 256, 0, stream>>>(xb, wcat, Cqkv, 1024, 3072, 2048);
  postproc<<<6144, 256, 0, stream>>>(Cqkv, fcos, fsin, qrope, kfull, newk, newv);
  vtr<<<dim3(32, 16), 256, 0, stream>>>(vc, newv, vTf);
  attn_split<<<512, 512, 0, stream>>>(qrope, kfull, vTf, mask, po, ml);
  attn_combine<<<8192, 256, 0, stream>>>(po, ml, aout);
  gemm_bt<<<dim3(8, 16), 256, 0, stream>>>(aout, wob, out_f, 1024, 2048, 2048);
}

// Round 10
// 147.546 us; speedup vs baseline: 1.8831x; 1.0007x over previous
//
#include <hip/hip_runtime.h>

typedef __attribute__((ext_vector_type(8))) short bf16x8;
typedef __attribute__((ext_vector_type(4))) float f32x4;
typedef unsigned short u16;

#define MFMA16(a, b, c) __builtin_amdgcn_mfma_f32_16x16x32_bf16(a, b, c, 0, 0, 0)
#define GLL(srcp, dstp) __builtin_amdgcn_global_load_lds(                      \
    (const __attribute__((address_space(1))) void*)(srcp),                     \
    (__attribute__((address_space(3))) void*)(dstp), 16, 0, 0)

__device__ __forceinline__ u16 f2b(float f) {
  union { float f; unsigned u; } a; a.f = f;
  return (u16)((a.u + 0x7FFFu + ((a.u >> 16) & 1u)) >> 16);
}

// ---------------- fused prep: f32->bf16 converts + k_cache copy ----------------
__global__ __launch_bounds__(256) void prep(const float* __restrict__ x,
                                            const float* __restrict__ wq,
                                            const float* __restrict__ wk,
                                            const float* __restrict__ wv,
                                            const float* __restrict__ wo,
                                            const float* __restrict__ kc,
                                            u16* __restrict__ xb,
                                            u16* __restrict__ wcat,
                                            u16* __restrict__ wob,
                                            u16* __restrict__ kfull) {
  const int c = blockIdx.x * 256 + threadIdx.x;
  const float* src;
  u16* dst;
  if (c < 524288) {
    src = x + (size_t)c * 4; dst = xb + (size_t)c * 4;
  } else if (c < 1572864) {
    size_t l = c - 524288; src = wq + l * 4; dst = wcat + l * 4;
  } else if (c < 1835008) {
    size_t l = c - 1572864; src = wk + l * 4; dst = wcat + 4194304 + l * 4;
  } else if (c < 2097152) {
    size_t l = c - 1835008; src = wv + l * 4; dst = wcat + 5242880 + l * 4;
  } else if (c < 3145728) {
    size_t l = c - 2097152; src = wo + l * 4; dst = wob + l * 4;
  } else {
    int l = c - 3145728;
    int bh = l / 24576, r = l - bh * 24576;
    src = kc + (size_t)bh * 98304 + (size_t)r * 4;
    dst = kfull + (size_t)bh * 131072 + (size_t)r * 4;
  }
  const float4 v = *(const float4*)src;
  ushort4 o;
  o.x = f2b(v.x); o.y = f2b(v.y); o.z = f2b(v.z); o.w = f2b(v.w);
  *(ushort4*)dst = o;
}

// unified V transpose -> vT [16][64][2048] bf16
__global__ __launch_bounds__(256) void vtr(const float* __restrict__ vc,
                                           const float* __restrict__ newv,
                                           u16* __restrict__ vT) {
  __shared__ float tile[64][65];
  const int kt = blockIdx.x, bh = blockIdx.y;
  const float* src;
  int colbase;
  if (kt < 24) {
    src = vc + ((size_t)bh * 1536 + (size_t)kt * 64) * 64;
    colbase = kt * 64;
  } else {
    src = newv + ((size_t)bh * 512 + (size_t)(kt - 24) * 64) * 64;
    colbase = 1536 + (kt - 24) * 64;
  }
  const int t = threadIdx.x;
#pragma unroll
  for (int j = 0; j < 4; j++) {
    int e = t + j * 256;            // 0..1023 chunks of 4
    int r = e >> 4, c = (e & 15) * 4;
    float4 v = *(const float4*)(src + (size_t)r * 64 + c);
    tile[r][c] = v.x; tile[r][c + 1] = v.y; tile[r][c + 2] = v.z; tile[r][c + 3] = v.w;
  }
  __syncthreads();
  int d = t >> 2, kv0 = (t & 3) * 16;
  u16* dst = vT + ((size_t)bh * 64 + d) * 2048 + colbase + kv0;
#pragma unroll
  for (int i = 0; i < 16; i++) dst[i] = f2b(tile[kv0 + i][d]);
}

// ---------------- GEMM: C[M][N] = A[M][K] * B[N][K]^T  (bf16 in, f32 out) ----------------
// 128x128 tile, BK=64, depth-3 pipeline (4 LDS buffers), counted vmcnt + raw barrier.
__global__ __launch_bounds__(256, 1) void gemm_bt(const u16* __restrict__ A,
                                                  const u16* __restrict__ B,
                                                  float* __restrict__ C,
                                                  int M, int N, int K) {
  __shared__ __attribute__((aligned(16))) u16 As[4][8192];  // 4 bufs x 128x64
  __shared__ __attribute__((aligned(16))) u16 Bs[4][8192];  // 128 KB total
  const int t = threadIdx.x;
  const int lane = t & 63, w = t >> 6;
  const int wr = (w >> 1) * 64, wc = (w & 1) * 64;
  const int g = lane >> 4, cc = lane & 15;
  const size_t row0 = (size_t)blockIdx.x * 128, col0 = (size_t)blockIdx.y * 128;

  const int lr = lane >> 3, lc = lane & 7;
  const int swz = lc ^ lr;
  const u16* aS = A + (row0 + w * 32 + lr) * (size_t)K + swz * 8;
  const u16* bS = B + (col0 + w * 32 + lr) * (size_t)K + swz * 8;

  f32x4 acc[4][4] = {};

#define GSTAGE(bufi, kk0)                                                      \
  {                                                                            \
    _Pragma("unroll") for (int i = 0; i < 4; i++) {                            \
      GLL(aS + (size_t)(i * 8) * K + (kk0), &As[bufi][(w * 32 + i * 8) * 64]); \
      GLL(bS + (size_t)(i * 8) * K + (kk0), &Bs[bufi][(w * 32 + i * 8) * 64]); \
    }                                                                          \
  }

  const int niter = K >> 6;  // >= 3 required (K=2048 -> 32)
  GSTAGE(0, 0);
  GSTAGE(1, 64);
  GSTAGE(2, 128);
  asm volatile("s_waitcnt vmcnt(16)" ::: "memory");
  __builtin_amdgcn_s_barrier();

  for (int it = 0; it < niter; ++it) {
    const int buf = it & 3;
    if (it + 3 < niter) GSTAGE((it + 3) & 3, (it + 3) * 64);
    bf16x8 av[4][2], bv[4][2];
#pragma unroll
    for (int m = 0; m < 4; m++) {
      const int row = wr + m * 16 + cc;
#pragma unroll
      for (int kk = 0; kk < 2; kk++)
        av[m][kk] = *(const bf16x8*)(&As[buf][row * 64 + (((kk * 4 + g) ^ (cc & 7)) * 8)]);
    }
#pragma unroll
    for (int n = 0; n < 4; n++) {
      const int row = wc + n * 16 + cc;
#pragma unroll
      for (int kk = 0; kk < 2; kk++)
        bv[n][kk] = *(const bf16x8*)(&Bs[buf][row * 64 + (((kk * 4 + g) ^ (cc & 7)) * 8)]);
    }
#pragma unroll
    for (int kk = 0; kk < 2; kk++)
#pragma unroll
      for (int m = 0; m < 4; m++)
#pragma unroll
        for (int n = 0; n < 4; n++)
          acc[m][n] = MFMA16(av[m][kk], bv[n][kk], acc[m][n]);
    // end-of-iter: wait only until the NEXT tile's stages are guaranteed done
    if (it + 4 <= niter) {
      asm volatile("s_waitcnt vmcnt(16)" ::: "memory");
    } else if (it + 3 == niter) {
      asm volatile("s_waitcnt vmcnt(8)" ::: "memory");
    } else if (it + 2 == niter) {
      asm volatile("s_waitcnt vmcnt(0)" ::: "memory");
    }
    if (it + 1 < niter) __builtin_amdgcn_s_barrier();
  }
#undef GSTAGE
#pragma unroll
  for (int m = 0; m < 4; m++)
#pragma unroll
    for (int n = 0; n < 4; n++)
#pragma unroll
      for (int r = 0; r < 4; r++)
        C[(row0 + wr + m * 16 + g * 4 + r) * N + (col0 + wc + n * 16 + cc)] = acc[m][n][r];
}

// ---------------- RoPE + scatter (no vT writes — vtr handles them) ----------------
__global__ __launch_bounds__(256) void postproc(const float* __restrict__ Cqkv,
                                                const float* __restrict__ fcos,
                                                const float* __restrict__ fsin,
                                                u16* __restrict__ qrope,
                                                u16* __restrict__ kfull,
                                                float* __restrict__ newk,
                                                float* __restrict__ newv) {
  int idx = blockIdx.x * 256 + threadIdx.x;
  if (idx >= 1024 * 1536) return;
  int m = idx / 1536, p = idx - m * 1536;
  int b = m >> 9, s = m & 511;
  const float* row = Cqkv + (size_t)m * 3072;
  if (p < 1280) {
    bool isq = p < 1024;
    int pk = isq ? p : p - 1024;
    int h = pk >> 5, i = pk & 31;
    int colbase = (isq ? 0 : 2048) + h * 64 + 2 * i;
    float xr = row[colbase], xi = row[colbase + 1];
    float co = fcos[s * 32 + i], si = fsin[s * 32 + i];
    float orr = xr * co - xi * si;
    float oii = xr * si + xi * co;
    if (isq) {
      u16* dst = qrope + (((size_t)(b * 32 + h) * 512 + s) * 64 + 2 * i);
      dst[0] = f2b(orr); dst[1] = f2b(oii);
    } else {
      size_t o0 = ((size_t)(b * 8 + h) * 512 + s) * 64 + 2 * i;
      newk[o0] = orr; newk[o0 + 1] = oii;
      u16* kf = kfull + (((size_t)(b * 8 + h) * 2048 + 1536 + s) * 64 + 2 * i);
      kf[0] = f2b(orr); kf[1] = f2b(oii);
    }
  } else {
    int pv = p - 1280;
    int h = pv >> 5, i = pv & 31;
    float v0 = row[2560 + h * 64 + 2 * i], v1 = row[2560 + h * 64 + 2 * i + 1];
    size_t o0 = ((size_t)(b * 8 + h) * 512 + s) * 64 + 2 * i;
    newv[o0] = v0; newv[o0 + 1] = v1;
  }
}

// ---------------- flash attention: 8-wave blocks, KV-split 2-way ----------------
// 4-deep LDS pipeline, raw s_barrier + counted vmcnt (T3/T4), setprio on MFMA (T5).
__global__ __launch_bounds__(512, 4) void attn_split(const u16* __restrict__ qrope,
                                                     const u16* __restrict__ kfull,
                                                     const u16* __restrict__ vT,
                                                     const float* __restrict__ mask,
                                                     float* __restrict__ po,
                                                     float* __restrict__ ml) {
  __shared__ __attribute__((aligned(16))) u16 Ks[4][4096];  // [buf][64 kv][64 d] 32KB
  __shared__ __attribute__((aligned(16))) u16 Vs[4][4096];  // [buf][64 d][64 kv] 32KB
  __shared__ __attribute__((aligned(16))) u16 P_lds[8192];  // 8 waves x 16x64   16KB
  const int t = threadIdx.x, lane = t & 63, w = t >> 6;  // w in 0..7
  const int g = lane >> 4, cc = lane & 15;
  // XCD-bijective swizzle: 512 blocks -> 8 chunks of 64 (8 bh per XCD)
  const int p = blockIdx.x;
  const int v = (p & 7) * 64 + (p >> 3);
  const int bh = v >> 3, qt = (v >> 1) & 3, sp = v & 1;
  const int b = bh >> 5, h = bh & 31;
  const int bhkv = b * 8 + (h >> 2);
  const int s0 = qt * 128 + w * 16;
  const int j0beg = sp * 1024;

  const int lr = lane >> 3, lc = lane & 7;
  const int swzc = lc ^ lr;  // pre-swizzled source granule column

  bf16x8 qa0, qa1;
  {
    const u16* qb = qrope + ((size_t)bh * 512 + s0 + cc) * 64 + g * 8;
    qa0 = *(const bf16x8*)qb;
    qa1 = *(const bf16x8*)(qb + 32);
  }
  float mrow[4], lsum[4];
  f32x4 o[4] = {};
#pragma unroll
  for (int r = 0; r < 4; r++) { mrow[r] = -1e30f; lsum[r] = 0.0f; }

  u16* Pw = P_lds + w * 1024;
  const float* mbase = mask + (size_t)(s0 + g * 4) * 2048 + cc;
  // wave w stages rows w*8 + lr of each 64-row tile (1 GLL for K, 1 for V)
  const u16* ksrc0 = kfull + (size_t)bhkv * 131072 + (size_t)(w * 8 + lr) * 64 + swzc * 8;
  const u16* vsrc0 = vT + ((size_t)bhkv * 64 + w * 8 + lr) * 2048 + swzc * 8;

  // prologue: stage tiles 0,1,2 into bufs 0,1,2 (6 GLLs per wave)
#pragma unroll
  for (int pt = 0; pt < 3; ++pt) {
    GLL(ksrc0 + (size_t)(j0beg + pt * 64) * 64, &Ks[pt][w * 512]);
    GLL(vsrc0 + (j0beg + pt * 64), &Vs[pt][w * 512]);
  }

  for (int it = 0; it < 16; ++it) {
    const int buf = it & 3;
    const int j0 = j0beg + it * 64;
    // tile `it` staged 3 iters ago; wait only for it (outstanding = newer tiles)
    if (it < 14) {
      asm volatile("s_waitcnt vmcnt(4)" ::: "memory");
    } else if (it == 14) {
      asm volatile("s_waitcnt vmcnt(2)" ::: "memory");
    } else {
      asm volatile("s_waitcnt vmcnt(0)" ::: "memory");
    }
    __builtin_amdgcn_s_barrier();  // all waves' tile-it loads landed; iter it-1 reads closed

    // mask loads FIRST: their use-wait retires only OLDER GLLs (already landed)
    float mk[4][4];
#pragma unroll
    for (int r = 0; r < 4; r++)
#pragma unroll
      for (int jb = 0; jb < 4; jb++)
        mk[r][jb] = mbase[(size_t)r * 2048 + j0 + jb * 16];
    __builtin_amdgcn_sched_barrier(0);  // keep mask loads issued before next GLLs
    if (it < 13) {  // stage tile it+3 into buf (it+3)&3 (overwrites tile it-1's buf)
      GLL(ksrc0 + (size_t)(j0 + 192) * 64, &Ks[(it + 3) & 3][w * 512]);
      GLL(vsrc0 + (j0 + 192), &Vs[(it + 3) & 3][w * 512]);
    }

    // QK^T from LDS (swizzled reads)
    f32x4 sc[4];
    __builtin_amdgcn_s_setprio(1);
#pragma unroll
    for (int jb = 0; jb < 4; jb++) {
      const bf16x8 k0 = *(const bf16x8*)(&Ks[buf][(jb * 16 + cc) * 64 + ((g ^ (cc & 7)) * 8)]);
      const bf16x8 k1 =
          *(const bf16x8*)(&Ks[buf][(jb * 16 + cc) * 64 + (((g + 4) ^ (cc & 7)) * 8)]);
      f32x4 z = {0.f, 0.f, 0.f, 0.f};
      z = MFMA16(qa0, k0, z);
      z = MFMA16(qa1, k1, z);
      sc[jb] = z;
    }
    __builtin_amdgcn_s_setprio(0);
    // softmax: ballot-gated defer-max, per-lane deferred sum
    float pp[4][4];
#pragma unroll
    for (int r = 0; r < 4; r++) {
#pragma unroll
      for (int jb = 0; jb < 4; jb++)
        pp[r][jb] = sc[jb][r] * 0.125f + mk[r][jb];
      const float lm = fmaxf(fmaxf(pp[r][0], pp[r][1]), fmaxf(pp[r][2], pp[r][3]));
      if (__any(lm > mrow[r] + 8.0f)) {  // rare after iter 0
        float tm = lm;
#pragma unroll
        for (int off = 1; off < 16; off <<= 1) tm = fmaxf(tm, __shfl_xor(tm, off, 64));
        const float newm = fmaxf(mrow[r], tm);
        const float corr = __expf(mrow[r] - newm);
        mrow[r] = newm;
        lsum[r] *= corr;
#pragma unroll
        for (int db = 0; db < 4; db++) o[db][r] *= corr;
      }
      float ps = 0.f;
#pragma unroll
      for (int jb = 0; jb < 4; jb++) { pp[r][jb] = __expf(pp[r][jb] - mrow[r]); ps += pp[r][jb]; }
      lsum[r] += ps;
      const int rowb = (g * 4 + r) * 128;
      const int sw = ((g * 4 + r) & 7) << 4;
#pragma unroll
      for (int jb = 0; jb < 4; jb++)
        Pw[((rowb + (jb * 16 + cc) * 2) ^ sw) >> 1] = f2b(pp[r][jb]);
    }
    // PV from LDS V (swizzled reads)
    __builtin_amdgcn_s_setprio(1);
#pragma unroll
    for (int kk = 0; kk < 2; kk++) {
      const bf16x8 pa =
          *(const bf16x8*)(Pw + (((cc * 128 + kk * 64 + g * 16) ^ ((cc & 7) << 4)) >> 1));
#pragma unroll
      for (int db = 0; db < 4; db++) {
        const bf16x8 vf =
            *(const bf16x8*)(&Vs[buf][(db * 16 + cc) * 64 + (((kk * 4 + g) ^ (cc & 7)) * 8)]);
        o[db] = MFMA16(pa, vf, o[db]);
      }
    }
    __builtin_amdgcn_s_setprio(0);
    // no end-of-iter barrier: next iter's vmcnt+barrier provides the sync
  }
#pragma unroll
  for (int r = 0; r < 4; r++) {
    float ps = lsum[r];
#pragma unroll
    for (int off = 1; off < 16; off <<= 1) ps += __shfl_xor(ps, off, 64);
    const size_t row = (size_t)bh * 512 + s0 + g * 4 + r;
    float* dst = po + (row * 2 + sp) * 64 + cc;
#pragma unroll
    for (int db = 0; db < 4; db++) dst[db * 16] = o[db][r];
    if (cc == 0) {
      float2* mlp = (float2*)ml;
      mlp[row * 2 + sp] = make_float2(mrow[r], ps);
    }
  }
}

// combine 2 splits -> aout bf16 [1024][2048] (b,s, h*64+d)
__global__ __launch_bounds__(256) void attn_combine(const float* __restrict__ po,
                                                    const float* __restrict__ ml,
                                                    u16* __restrict__ aout) {
  const int t = threadIdx.x;
  const int row = blockIdx.x * 4 + (t >> 6);  // bh*512 + s
  const int d = t & 63;
  const int bh = row >> 9, s = row & 511;
  const int b = bh >> 5, h = bh & 31;
  const float2* mlp = (const float2*)ml;
  const float2 m0 = mlp[row * 2 + 0], m1 = mlp[row * 2 + 1];
  const float M = fmaxf(m0.x, m1.x);
  const float w0 = __expf(m0.x - M), w1 = __expf(m1.x - M);
  const float L = m0.y * w0 + m1.y * w1;
  const float o = po[(size_t)(row * 2 + 0) * 64 + d] * w0 +
                  po[(size_t)(row * 2 + 1) * 64 + d] * w1;
  aout[((size_t)(b * 512 + s)) * 2048 + h * 64 + d] = f2b(o / L);
}

// ---------------- launch ----------------
extern "C" void kernel_launch(void* const* d_in, const int* in_sizes, int n_in,
                              void* d_out, int out_size, void* d_ws, size_t ws_size,
                              hipStream_t stream) {
  (void)in_sizes; (void)n_in; (void)out_size; (void)ws_size;
  const float* x    = (const float*)d_in[0];
  const float* fcos = (const float*)d_in[1];
  const float* fsin = (const float*)d_in[2];
  const float* kc   = (const float*)d_in[3];
  const float* vc   = (const float*)d_in[4];
  const float* mask = (const float*)d_in[5];
  const float* wq   = (const float*)d_in[6];
  const float* wk   = (const float*)d_in[7];
  const float* wv   = (const float*)d_in[8];
  const float* wo   = (const float*)d_in[9];

  float* out_f = (float*)d_out;                 // [2][512][2048]
  float* newk  = out_f + 2097152;               // [2][8][512][64]
  float* newv  = out_f + 2621440;               // [2][8][512][64]

  u16*   xb    = (u16*)d_ws;                    // 4MB   (dead after gemm1)
  u16*   wcat  = xb + 2097152;                  // 12MB  (dead after gemm1)
  u16*   wob   = wcat + 6291456;                // 8MB   (live until gemm2)
  float* Cqkv  = (float*)(wob + 4194304);       // 12MB  (dead after postproc)
  u16*   qrope = (u16*)(Cqkv + 3145728);        // 4MB
  u16*   kfull = qrope + 2097152;               // 4MB
  u16*   vTf   = kfull + 2097152;               // 4MB
  u16*   aout  = vTf + 2097152;                 // 4MB
  // aliases (live only during attention phase):
  float* po    = (float*)d_ws;                  // 16MB over xb+wcat
  float* ml    = Cqkv;                          // 0.5MB over Cqkv (dead after postproc)

  prep<<<13824, 256, 0, stream>>>(x, wq, wk, wv, wo, kc, xb, wcat, wob, kfull);

  gemm_bt<<<dim3(8, 24), 256, 0, stream>>>(xb, wcat, Cqkv, 1024, 3072, 2048);
  postproc<<<6144, 256, 0, stream>>>(Cqkv, fcos, fsin, qrope, kfull, newk, newv);
  vtr<<<dim3(32, 16), 256, 0, stream>>>(vc, newv, vTf);
  attn_split<<<512, 512, 0, stream>>>(qrope, kfull, vTf, mask, po, ml);
  attn_combine<<<8192, 256, 0, stream>>>(po, ml, aout);
  gemm_bt<<<dim3(8, 16), 256, 0, stream>>>(aout, wob, out_f, 1024, 2048, 2048);
}